// Round 2
// baseline (13549.152 us; speedup 1.0000x reference)
//
#include <hip/hip_runtime.h>
#include <hip/hip_bf16.h>
#include <math.h>

#define NNODES 50000
#define NEDGES 800000
#define NGRAPHS 128

// ---------------------------------------------------------------- CSR build
__global__ void count_edges(const int* __restrict__ ei, int* __restrict__ cnt) {
    int e = blockIdx.x * 256 + threadIdx.x;
    if (e < NEDGES) atomicAdd(&cnt[ei[NEDGES + e]], 1);
}

__global__ void scan_counts(const int* __restrict__ cnt, int* __restrict__ rowptr,
                            int* __restrict__ wpos) {
    __shared__ int part[256];
    const int t = threadIdx.x;
    const int CHK = (NNODES + 255) / 256;     // 196
    int lo = t * CHK, hi = min(lo + CHK, NNODES);
    int s = 0;
    for (int i = lo; i < hi; ++i) s += cnt[i];
    part[t] = s;
    __syncthreads();
    for (int off = 1; off < 256; off <<= 1) {
        int v = (t >= off) ? part[t - off] : 0;
        __syncthreads();
        part[t] += v;
        __syncthreads();
    }
    int run = (t == 0) ? 0 : part[t - 1];
    for (int i = lo; i < hi; ++i) { rowptr[i] = run; wpos[i] = run; run += cnt[i]; }
    if (t == 255) rowptr[NNODES] = part[255];
}

__global__ void fill_csr(const int* __restrict__ ei, int* __restrict__ wpos,
                         int* __restrict__ colsrc) {
    int e = blockIdx.x * 256 + threadIdx.x;
    if (e < NEDGES) {
        int d = ei[NEDGES + e];
        int slot = atomicAdd(&wpos[d], 1);
        colsrc[slot] = ei[e];            // store src node id
    }
}

// ------------------------------------------------- fused head weight (wl@wl2)
__global__ void fuse_wl(const float* __restrict__ wl, const float* __restrict__ bl,
                        const float* __restrict__ wl2, const float* __restrict__ bl2,
                        float* __restrict__ wf, float* __restrict__ bf) {
    int t = threadIdx.x;                 // 128 threads
    float s = 0.f;
    for (int j = 0; j < 128; ++j) s += wl[t * 128 + j] * wl2[j];
    wf[t] = s;
    if (t == 0) {
        float s2 = 0.f;
        for (int j = 0; j < 128; ++j) s2 += bl[j] * wl2[j];
        bf[0] = s2 + bl2[0];
    }
}

// ---------------------------------------------------------------- fused GEMM
// O[sel] = F @ W[sel] + b[sel] for sel in {Q,K,V,skip}; F is (NNODES x 128).
// Tile 128 rows x 64 cols. K chunked by 32. Single LDS A-buffer, reg-staged
// prefetch (T14 split). NO local arrays anywhere in the hot path (rule #20 --
// round-1 version had av[]/bb[]/areg[] in scratch -> 2.6 GB of spill writes).
#define ROWFMA(ACC, AV)                                                      \
    ACC.x = fmaf((AV), bq4.x, ACC.x); ACC.y = fmaf((AV), bq4.y, ACC.y);      \
    ACC.z = fmaf((AV), bq4.z, ACC.z); ACC.w = fmaf((AV), bq4.w, ACC.w);

__global__ __launch_bounds__(256, 3)
void gemm_qkvs(const float* __restrict__ F,
               const float* __restrict__ wq, const float* __restrict__ bq,
               const float* __restrict__ wk, const float* __restrict__ bk,
               const float* __restrict__ wv, const float* __restrict__ bv,
               const float* __restrict__ wsk, const float* __restrict__ bsk,
               float* __restrict__ Q, float* __restrict__ Kp,
               float* __restrict__ V, float* __restrict__ H) {
    __shared__ __align__(16) float Bs[128][64];     // 32 KB (full K for 64 cols)
    __shared__ __align__(16) float As[32][132];     // 16.9 KB, transposed, padded
    const int tid = threadIdx.x;
    const int bn  = blockIdx.y;
    const int sel = bn >> 1;
    const int c0  = (bn & 1) * 64;
    const float* W    = sel == 0 ? wq : sel == 1 ? wk : sel == 2 ? wv : wsk;
    const float* bias = sel == 0 ? bq : sel == 1 ? bk : sel == 2 ? bv : bsk;
    float* O          = sel == 0 ? Q  : sel == 1 ? Kp : sel == 2 ? V  : H;

    {   // stage B slice (128 x 64) once
        int r  = tid >> 4;
        int cq = (tid & 15) * 4;
#pragma unroll
        for (int p = 0; p < 8; ++p)
            *(float4*)&Bs[r + p * 16][cq] = *(const float4*)&W[(r + p * 16) * 128 + c0 + cq];
    }
    const int m0   = blockIdx.x * 128;
    const int lrow = tid >> 3;           // 0..31
    const int lkq  = (tid & 7) * 4;      // 0,4,..,28
    const int g0 = m0 + lrow, g1 = g0 + 32, g2 = g0 + 64, g3 = g0 + 96;
    const float4 f4z = make_float4(0.f, 0.f, 0.f, 0.f);
    float4 s0, s1, s2, s3;               // staging registers (global -> LDS)

#define LOADA(KC)                                                              \
    s0 = (g0 < NNODES) ? *(const float4*)&F[(size_t)g0 * 128 + (KC) * 32 + lkq] : f4z; \
    s1 = (g1 < NNODES) ? *(const float4*)&F[(size_t)g1 * 128 + (KC) * 32 + lkq] : f4z; \
    s2 = (g2 < NNODES) ? *(const float4*)&F[(size_t)g2 * 128 + (KC) * 32 + lkq] : f4z; \
    s3 = (g3 < NNODES) ? *(const float4*)&F[(size_t)g3 * 128 + (KC) * 32 + lkq] : f4z;

#define WRITEA()                                                               \
    As[lkq + 0][lrow]      = s0.x; As[lkq + 1][lrow]      = s0.y;              \
    As[lkq + 2][lrow]      = s0.z; As[lkq + 3][lrow]      = s0.w;              \
    As[lkq + 0][lrow + 32] = s1.x; As[lkq + 1][lrow + 32] = s1.y;              \
    As[lkq + 2][lrow + 32] = s1.z; As[lkq + 3][lrow + 32] = s1.w;              \
    As[lkq + 0][lrow + 64] = s2.x; As[lkq + 1][lrow + 64] = s2.y;              \
    As[lkq + 2][lrow + 64] = s2.z; As[lkq + 3][lrow + 64] = s2.w;              \
    As[lkq + 0][lrow + 96] = s3.x; As[lkq + 1][lrow + 96] = s3.y;              \
    As[lkq + 2][lrow + 96] = s3.z; As[lkq + 3][lrow + 96] = s3.w;

    float4 a0c = f4z, a1c = f4z, a2c = f4z, a3c = f4z;   // acc rows 0..3
    float4 a4c = f4z, a5c = f4z, a6c = f4z, a7c = f4z;   // acc rows 4..7
    const int tr = (tid >> 4) * 8;
    const int tc = (tid & 15) * 4;

    LOADA(0)
    WRITEA()
    __syncthreads();
#pragma unroll
    for (int kc = 0; kc < 4; ++kc) {
        if (kc < 3) { LOADA(kc + 1) }    // issue next chunk's global loads early
#pragma unroll
        for (int k = 0; k < 32; ++k) {
            const float4 bq4 = *(const float4*)&Bs[kc * 32 + k][tc];
            const float4 av0 = *(const float4*)&As[k][tr];
            const float4 av1 = *(const float4*)&As[k][tr + 4];
            ROWFMA(a0c, av0.x) ROWFMA(a1c, av0.y) ROWFMA(a2c, av0.z) ROWFMA(a3c, av0.w)
            ROWFMA(a4c, av1.x) ROWFMA(a5c, av1.y) ROWFMA(a6c, av1.z) ROWFMA(a7c, av1.w)
        }
        __syncthreads();
        if (kc < 3) {
            WRITEA()
            __syncthreads();
        }
    }
    const float4 bias4 = *(const float4*)&bias[c0 + tc];
#define STORE_ROW(I, ACC)                                                      \
    {                                                                          \
        int gr = m0 + tr + (I);                                                \
        if (gr < NNODES) {                                                     \
            float4 o = make_float4(ACC.x + bias4.x, ACC.y + bias4.y,           \
                                   ACC.z + bias4.z, ACC.w + bias4.w);          \
            *(float4*)&O[(size_t)gr * 128 + c0 + tc] = o;                      \
        }                                                                      \
    }
    STORE_ROW(0, a0c) STORE_ROW(1, a1c) STORE_ROW(2, a2c) STORE_ROW(3, a3c)
    STORE_ROW(4, a4c) STORE_ROW(5, a5c) STORE_ROW(6, a6c) STORE_ROW(7, a7c)
#undef LOADA
#undef WRITEA
#undef STORE_ROW
}

// --------------------------------------------- per-dst-node online softmax agg
// block = 128 threads (channel c = tid; head = c>>5), one block per node.
// H holds the skip term on entry; on exit H = relu(skip + attn_msg).
__global__ __launch_bounds__(128)
void attn_agg(const float* __restrict__ Q, const float* __restrict__ K,
              const float* __restrict__ V, float* __restrict__ H,
              const int* __restrict__ rowptr, const int* __restrict__ colsrc) {
    const int n = blockIdx.x;
    const int c = threadIdx.x;
    const float q = Q[n * 128 + c] * 0.17677669529663687f;   // 1/sqrt(32) folded
    const int beg = rowptr[n], end = rowptr[n + 1];
    float m = -INFINITY, s = 0.f, acc = 0.f;
    float kN = 0.f, vN = 0.f;
    if (beg < end) {
        int s0 = colsrc[beg];
        kN = K[s0 * 128 + c];
        vN = V[s0 * 128 + c];
    }
    for (int i = beg; i < end; ++i) {
        float kc = kN, vc = vN;
        if (i + 1 < end) {               // prefetch next edge's K/V
            int s2 = colsrc[i + 1];
            kN = K[s2 * 128 + c];
            vN = V[s2 * 128 + c];
        }
        float p = q * kc;
#pragma unroll
        for (int off = 16; off > 0; off >>= 1) p += __shfl_xor(p, off, 32);
        float nm = fmaxf(m, p);
        float sc = __expf(m - nm);
        float w  = __expf(p - nm);
        s   = s * sc + w;
        acc = acc * sc + w * vc;
        m = nm;
    }
    float out = H[n * 128 + c];
    if (end > beg) out += acc / s;
    H[n * 128 + c] = fmaxf(out, 0.f);
}

// ------------------------------------------------------------- head + pooling
__global__ __launch_bounds__(256)
void pool_nodes(const float* __restrict__ H2, const float* __restrict__ wf,
                const float* __restrict__ bf, const int* __restrict__ batch,
                float* __restrict__ gsum, float* __restrict__ gcnt) {
    int node = blockIdx.x * 4 + (threadIdx.x >> 6);
    int lane = threadIdx.x & 63;
    if (node >= NNODES) return;
    float r = H2[node * 128 + lane] * wf[lane] +
              H2[node * 128 + 64 + lane] * wf[64 + lane];
#pragma unroll
    for (int off = 32; off > 0; off >>= 1) r += __shfl_xor(r, off, 64);
    if (lane == 0) {
        int g = batch[node];
        atomicAdd(&gsum[g], r + bf[0]);
        atomicAdd(&gcnt[g], 1.f);
    }
}

__global__ void finalize_pool(const float* __restrict__ gsum,
                              const float* __restrict__ gcnt, float* __restrict__ out) {
    int g = threadIdx.x;
    if (g < NGRAPHS) out[g] = gsum[g] / fmaxf(gcnt[g], 1.f);
}

// ---------------------------------------------------------------------- launch
extern "C" void kernel_launch(void* const* d_in, const int* in_sizes, int n_in,
                              void* d_out, int out_size, void* d_ws, size_t ws_size,
                              hipStream_t stream) {
    const float* x     = (const float*)d_in[0];
    const int*   ei    = (const int*)d_in[1];
    const int*   batch = (const int*)d_in[2];
    const float* wq1 = (const float*)d_in[3];  const float* bq1 = (const float*)d_in[4];
    const float* wk1 = (const float*)d_in[5];  const float* bk1 = (const float*)d_in[6];
    const float* wv1 = (const float*)d_in[7];  const float* bv1 = (const float*)d_in[8];
    const float* ws1 = (const float*)d_in[9];  const float* bs1 = (const float*)d_in[10];
    const float* wq2 = (const float*)d_in[11]; const float* bq2 = (const float*)d_in[12];
    const float* wk2 = (const float*)d_in[13]; const float* bk2 = (const float*)d_in[14];
    const float* wv2 = (const float*)d_in[15]; const float* bv2 = (const float*)d_in[16];
    const float* ws2 = (const float*)d_in[17]; const float* bs2 = (const float*)d_in[18];
    const float* wl  = (const float*)d_in[19]; const float* bl  = (const float*)d_in[20];
    const float* wl2 = (const float*)d_in[21]; const float* bl2 = (const float*)d_in[22];

    char* wsb = (char*)d_ws;
    size_t off = 0;
    auto carve = [&](size_t bytes) -> void* {
        void* p = wsb + off;
        off = (off + bytes + 255) & ~(size_t)255;
        return p;
    };
    const size_t NM = (size_t)NNODES * 128 * sizeof(float);   // 25.6 MB
    float* Q      = (float*)carve(NM);
    float* K      = (float*)carve(NM);
    float* V      = (float*)carve(NM);
    float* H1     = (float*)carve(NM);
    float* H2     = (float*)carve(NM);
    int*   rowptr = (int*)carve((NNODES + 1) * sizeof(int));
    int*   wpos   = (int*)carve(NNODES * sizeof(int));
    int*   cnt    = (int*)carve(NNODES * sizeof(int));
    int*   colsrc = (int*)carve(NEDGES * sizeof(int));
    float* wf     = (float*)carve(129 * sizeof(float));  // 128 fused weights + bias
    float* bf     = wf + 128;
    float* gsum   = (float*)carve(2 * NGRAPHS * sizeof(float));
    float* gcnt   = gsum + NGRAPHS;

    hipMemsetAsync(cnt, 0, NNODES * sizeof(int), stream);
    hipMemsetAsync(gsum, 0, 2 * NGRAPHS * sizeof(float), stream);

    count_edges<<<(NEDGES + 255) / 256, 256, 0, stream>>>(ei, cnt);
    scan_counts<<<1, 256, 0, stream>>>(cnt, rowptr, wpos);
    fill_csr<<<(NEDGES + 255) / 256, 256, 0, stream>>>(ei, wpos, colsrc);
    fuse_wl<<<1, 128, 0, stream>>>(wl, bl, wl2, bl2, wf, bf);

    dim3 ggrid((NNODES + 127) / 128, 8);
    // layer 1
    gemm_qkvs<<<ggrid, 256, 0, stream>>>(x, wq1, bq1, wk1, bk1, wv1, bv1, ws1, bs1,
                                         Q, K, V, H1);
    attn_agg<<<NNODES, 128, 0, stream>>>(Q, K, V, H1, rowptr, colsrc);
    // layer 2
    gemm_qkvs<<<ggrid, 256, 0, stream>>>(H1, wq2, bq2, wk2, bk2, wv2, bv2, ws2, bs2,
                                         Q, K, V, H2);
    attn_agg<<<NNODES, 128, 0, stream>>>(Q, K, V, H2, rowptr, colsrc);
    // fused head + mean pool
    pool_nodes<<<(NNODES + 3) / 4, 256, 0, stream>>>(H2, wf, bf, batch, gsum, gcnt);
    finalize_pool<<<1, 128, 0, stream>>>(gsum, gcnt, (float*)d_out);
}

// Round 3
// 1097.998 us; speedup vs baseline: 12.3399x; 12.3399x over previous
//
#include <hip/hip_runtime.h>
#include <hip/hip_bf16.h>
#include <math.h>

#define NNODES 50000
#define NEDGES 800000
#define NGRAPHS 128

// ---------------------------------------------------------------- CSR build
__global__ void count_edges(const int* __restrict__ ei, int* __restrict__ cnt) {
    int e = blockIdx.x * 256 + threadIdx.x;
    if (e < NEDGES) atomicAdd(&cnt[ei[NEDGES + e]], 1);
}

__global__ void scan_counts(const int* __restrict__ cnt, int* __restrict__ rowptr,
                            int* __restrict__ wpos) {
    __shared__ int part[256];
    const int t = threadIdx.x;
    const int CHK = (NNODES + 255) / 256;     // 196
    int lo = t * CHK, hi = min(lo + CHK, NNODES);
    int s = 0;
    for (int i = lo; i < hi; ++i) s += cnt[i];
    part[t] = s;
    __syncthreads();
    for (int off = 1; off < 256; off <<= 1) {
        int v = (t >= off) ? part[t - off] : 0;
        __syncthreads();
        part[t] += v;
        __syncthreads();
    }
    int run = (t == 0) ? 0 : part[t - 1];
    for (int i = lo; i < hi; ++i) { rowptr[i] = run; wpos[i] = run; run += cnt[i]; }
    if (t == 255) rowptr[NNODES] = part[255];
}

__global__ void fill_csr(const int* __restrict__ ei, int* __restrict__ wpos,
                         int* __restrict__ colsrc) {
    int e = blockIdx.x * 256 + threadIdx.x;
    if (e < NEDGES) {
        int d = ei[NEDGES + e];
        int slot = atomicAdd(&wpos[d], 1);
        colsrc[slot] = ei[e];            // store src node id
    }
}

// ------------------------------------------------- fused head weight (wl@wl2)
__global__ void fuse_wl(const float* __restrict__ wl, const float* __restrict__ bl,
                        const float* __restrict__ wl2, const float* __restrict__ bl2,
                        float* __restrict__ wf, float* __restrict__ bf) {
    int t = threadIdx.x;                 // 128 threads
    float s = 0.f;
    for (int j = 0; j < 128; ++j) s += wl[t * 128 + j] * wl2[j];
    wf[t] = s;
    if (t == 0) {
        float s2 = 0.f;
        for (int j = 0; j < 128; ++j) s2 += bl[j] * wl2[j];
        bf[0] = s2 + bl2[0];
    }
}

// ---------------------------------------------------------------- fused GEMM
// O[sel] = F @ W[sel] + b[sel], sel in {Q,K,V,skip}; F is (NNODES x 128).
// One block owns 64 rows and loops over all 8 (sel, col-half) output slices,
// restaging only the B slice (weights are L2-resident). A-tile (full K=128,
// transposed) is staged ONCE -> F read exactly once from HBM.
// Per-thread state: 4x4 acc in 4 named float4s + 2 temps (~35 VGPR) -- the
// rounds-1/2 scratch-spill disease (GBs of FETCH/WRITE) is structurally
// impossible here.
#define RF(ACC, AV)                                                           \
    ACC.x = fmaf((AV), b4.x, ACC.x); ACC.y = fmaf((AV), b4.y, ACC.y);         \
    ACC.z = fmaf((AV), b4.z, ACC.z); ACC.w = fmaf((AV), b4.w, ACC.w);

__global__ __launch_bounds__(256)
void gemm_qkvs(const float* __restrict__ F,
               const float* __restrict__ wq, const float* __restrict__ bq,
               const float* __restrict__ wk, const float* __restrict__ bk,
               const float* __restrict__ wv, const float* __restrict__ bv,
               const float* __restrict__ wsk, const float* __restrict__ bsk,
               float* __restrict__ Q, float* __restrict__ Kp,
               float* __restrict__ V, float* __restrict__ H) {
    __shared__ __align__(16) float As[128][68];   // [k][row], 34.8 KB
    __shared__ __align__(16) float Bs[128][68];   // [k][col], 34.8 KB
    const int t  = threadIdx.x;
    const int m0 = blockIdx.x * 64;

    {   // stage A tile: 64 rows x 128 k, transposed. Each thread: 8 float4.
        const int rl = t >> 2;                   // 0..63
        const int kb = (t & 3) * 32;             // 0,32,64,96
        const int gr = min(m0 + rl, NNODES - 1); // clamp tail (stores guarded)
#pragma unroll
        for (int p = 0; p < 8; ++p) {
            const float4 v = *(const float4*)&F[(size_t)gr * 128 + kb + p * 4];
            As[kb + p * 4 + 0][rl] = v.x;
            As[kb + p * 4 + 1][rl] = v.y;
            As[kb + p * 4 + 2][rl] = v.z;
            As[kb + p * 4 + 3][rl] = v.w;
        }
    }
    const int tr = (t >> 4) * 4;                 // acc row base 0..60
    const int tc = (t & 15) * 4;                 // acc col base 0..60
    const int kB = t >> 3;                       // B-stage row 0..31 (+p*32)
    const int cB = (t & 7) * 8;                  // B-stage col

    for (int sl = 0; sl < 8; ++sl) {
        const int sel = sl >> 1;
        const int c0  = (sl & 1) * 64;
        const float* W    = sel == 0 ? wq : sel == 1 ? wk : sel == 2 ? wv : wsk;
        const float* bias = sel == 0 ? bq : sel == 1 ? bk : sel == 2 ? bv : bsk;
        float* O          = sel == 0 ? Q  : sel == 1 ? Kp : sel == 2 ? V  : H;

#pragma unroll
        for (int p = 0; p < 4; ++p) {            // stage B slice 128 x 64
            const int k = kB + p * 32;
            *(float4*)&Bs[k][cB]     = *(const float4*)&W[k * 128 + c0 + cB];
            *(float4*)&Bs[k][cB + 4] = *(const float4*)&W[k * 128 + c0 + cB + 4];
        }
        __syncthreads();                         // Bs ready (and As on sl==0)

        float4 a0 = make_float4(0.f, 0.f, 0.f, 0.f);
        float4 a1 = a0, a2 = a0, a3 = a0;
#pragma unroll 4
        for (int k = 0; k < 128; ++k) {
            const float4 b4 = *(const float4*)&Bs[k][tc];
            const float4 av = *(const float4*)&As[k][tr];
            RF(a0, av.x) RF(a1, av.y) RF(a2, av.z) RF(a3, av.w)
        }
        __syncthreads();                         // readers done before restage

        const float4 bias4 = *(const float4*)&bias[c0 + tc];
#define STORE_ROW(I, ACC)                                                     \
        {                                                                     \
            const int gr = m0 + tr + (I);                                     \
            if (gr < NNODES) {                                                \
                const float4 o = make_float4(ACC.x + bias4.x, ACC.y + bias4.y,\
                                             ACC.z + bias4.z, ACC.w + bias4.w);\
                *(float4*)&O[(size_t)gr * 128 + c0 + tc] = o;                 \
            }                                                                 \
        }
        STORE_ROW(0, a0) STORE_ROW(1, a1) STORE_ROW(2, a2) STORE_ROW(3, a3)
#undef STORE_ROW
    }
}

// --------------------------------------------- per-dst-node online softmax agg
// block = 128 threads (channel c = tid; head = c>>5), one block per node.
// H holds the skip term on entry; on exit H = relu(skip + attn_msg).
__global__ __launch_bounds__(128)
void attn_agg(const float* __restrict__ Q, const float* __restrict__ K,
              const float* __restrict__ V, float* __restrict__ H,
              const int* __restrict__ rowptr, const int* __restrict__ colsrc) {
    const int n = blockIdx.x;
    const int c = threadIdx.x;
    const float q = Q[n * 128 + c] * 0.17677669529663687f;   // 1/sqrt(32) folded
    const int beg = rowptr[n], end = rowptr[n + 1];
    float m = -INFINITY, s = 0.f, acc = 0.f;
    float kN = 0.f, vN = 0.f;
    if (beg < end) {
        int s0 = colsrc[beg];
        kN = K[s0 * 128 + c];
        vN = V[s0 * 128 + c];
    }
    for (int i = beg; i < end; ++i) {
        float kc = kN, vc = vN;
        if (i + 1 < end) {               // prefetch next edge's K/V
            int s2 = colsrc[i + 1];
            kN = K[s2 * 128 + c];
            vN = V[s2 * 128 + c];
        }
        float p = q * kc;
#pragma unroll
        for (int off = 16; off > 0; off >>= 1) p += __shfl_xor(p, off, 32);
        float nm = fmaxf(m, p);
        float sc = __expf(m - nm);
        float w  = __expf(p - nm);
        s   = s * sc + w;
        acc = acc * sc + w * vc;
        m = nm;
    }
    float out = H[n * 128 + c];
    if (end > beg) out += acc / s;
    H[n * 128 + c] = fmaxf(out, 0.f);
}

// ------------------------------------------------------------- head + pooling
__global__ __launch_bounds__(256)
void pool_nodes(const float* __restrict__ H2, const float* __restrict__ wf,
                const float* __restrict__ bf, const int* __restrict__ batch,
                float* __restrict__ gsum, float* __restrict__ gcnt) {
    int node = blockIdx.x * 4 + (threadIdx.x >> 6);
    int lane = threadIdx.x & 63;
    if (node >= NNODES) return;
    float r = H2[node * 128 + lane] * wf[lane] +
              H2[node * 128 + 64 + lane] * wf[64 + lane];
#pragma unroll
    for (int off = 32; off > 0; off >>= 1) r += __shfl_xor(r, off, 64);
    if (lane == 0) {
        int g = batch[node];
        atomicAdd(&gsum[g], r + bf[0]);
        atomicAdd(&gcnt[g], 1.f);
    }
}

__global__ void finalize_pool(const float* __restrict__ gsum,
                              const float* __restrict__ gcnt, float* __restrict__ out) {
    int g = threadIdx.x;
    if (g < NGRAPHS) out[g] = gsum[g] / fmaxf(gcnt[g], 1.f);
}

// ---------------------------------------------------------------------- launch
extern "C" void kernel_launch(void* const* d_in, const int* in_sizes, int n_in,
                              void* d_out, int out_size, void* d_ws, size_t ws_size,
                              hipStream_t stream) {
    const float* x     = (const float*)d_in[0];
    const int*   ei    = (const int*)d_in[1];
    const int*   batch = (const int*)d_in[2];
    const float* wq1 = (const float*)d_in[3];  const float* bq1 = (const float*)d_in[4];
    const float* wk1 = (const float*)d_in[5];  const float* bk1 = (const float*)d_in[6];
    const float* wv1 = (const float*)d_in[7];  const float* bv1 = (const float*)d_in[8];
    const float* ws1 = (const float*)d_in[9];  const float* bs1 = (const float*)d_in[10];
    const float* wq2 = (const float*)d_in[11]; const float* bq2 = (const float*)d_in[12];
    const float* wk2 = (const float*)d_in[13]; const float* bk2 = (const float*)d_in[14];
    const float* wv2 = (const float*)d_in[15]; const float* bv2 = (const float*)d_in[16];
    const float* ws2 = (const float*)d_in[17]; const float* bs2 = (const float*)d_in[18];
    const float* wl  = (const float*)d_in[19]; const float* bl  = (const float*)d_in[20];
    const float* wl2 = (const float*)d_in[21]; const float* bl2 = (const float*)d_in[22];

    char* wsb = (char*)d_ws;
    size_t off = 0;
    auto carve = [&](size_t bytes) -> void* {
        void* p = wsb + off;
        off = (off + bytes + 255) & ~(size_t)255;
        return p;
    };
    const size_t NM = (size_t)NNODES * 128 * sizeof(float);   // 25.6 MB
    float* Q      = (float*)carve(NM);
    float* K      = (float*)carve(NM);
    float* V      = (float*)carve(NM);
    float* H1     = (float*)carve(NM);
    float* H2     = (float*)carve(NM);
    int*   rowptr = (int*)carve((NNODES + 1) * sizeof(int));
    int*   wpos   = (int*)carve(NNODES * sizeof(int));
    int*   cnt    = (int*)carve(NNODES * sizeof(int));
    int*   colsrc = (int*)carve(NEDGES * sizeof(int));
    float* wf     = (float*)carve(129 * sizeof(float));  // 128 fused weights + bias
    float* bf     = wf + 128;
    float* gsum   = (float*)carve(2 * NGRAPHS * sizeof(float));
    float* gcnt   = gsum + NGRAPHS;

    hipMemsetAsync(cnt, 0, NNODES * sizeof(int), stream);
    hipMemsetAsync(gsum, 0, 2 * NGRAPHS * sizeof(float), stream);

    count_edges<<<(NEDGES + 255) / 256, 256, 0, stream>>>(ei, cnt);
    scan_counts<<<1, 256, 0, stream>>>(cnt, rowptr, wpos);
    fill_csr<<<(NEDGES + 255) / 256, 256, 0, stream>>>(ei, wpos, colsrc);
    fuse_wl<<<1, 128, 0, stream>>>(wl, bl, wl2, bl2, wf, bf);

    const int ggrid = (NNODES + 63) / 64;      // 782 blocks, 8 slices each
    // layer 1
    gemm_qkvs<<<ggrid, 256, 0, stream>>>(x, wq1, bq1, wk1, bk1, wv1, bv1, ws1, bs1,
                                         Q, K, V, H1);
    attn_agg<<<NNODES, 128, 0, stream>>>(Q, K, V, H1, rowptr, colsrc);
    // layer 2
    gemm_qkvs<<<ggrid, 256, 0, stream>>>(H1, wq2, bq2, wk2, bk2, wv2, bv2, ws2, bs2,
                                         Q, K, V, H2);
    attn_agg<<<NNODES, 128, 0, stream>>>(Q, K, V, H2, rowptr, colsrc);
    // fused head + mean pool
    pool_nodes<<<(NNODES + 3) / 4, 256, 0, stream>>>(H2, wf, bf, batch, gsum, gcnt);
    finalize_pool<<<1, 128, 0, stream>>>(gsum, gcnt, (float*)d_out);
}

// Round 4
// 801.702 us; speedup vs baseline: 16.9005x; 1.3696x over previous
//
#include <hip/hip_runtime.h>
#include <hip/hip_bf16.h>
#include <math.h>

#define NNODES 50000
#define NEDGES 800000
#define NGRAPHS 128

// ---------------------------------------------------------------- CSR build
__global__ void count_edges(const int* __restrict__ ei, int* __restrict__ cnt) {
    int e = blockIdx.x * 256 + threadIdx.x;
    if (e < NEDGES) atomicAdd(&cnt[ei[NEDGES + e]], 1);
}

__global__ void scan_counts(const int* __restrict__ cnt, int* __restrict__ rowptr,
                            int* __restrict__ wpos) {
    __shared__ int part[256];
    const int t = threadIdx.x;
    const int CHK = (NNODES + 255) / 256;     // 196
    int lo = t * CHK, hi = min(lo + CHK, NNODES);
    int s = 0;
    for (int i = lo; i < hi; ++i) s += cnt[i];
    part[t] = s;
    __syncthreads();
    for (int off = 1; off < 256; off <<= 1) {
        int v = (t >= off) ? part[t - off] : 0;
        __syncthreads();
        part[t] += v;
        __syncthreads();
    }
    int run = (t == 0) ? 0 : part[t - 1];
    for (int i = lo; i < hi; ++i) { rowptr[i] = run; wpos[i] = run; run += cnt[i]; }
    if (t == 255) rowptr[NNODES] = part[255];
}

__global__ void fill_csr(const int* __restrict__ ei, int* __restrict__ wpos,
                         int* __restrict__ colsrc) {
    int e = blockIdx.x * 256 + threadIdx.x;
    if (e < NEDGES) {
        int d = ei[NEDGES + e];
        int slot = atomicAdd(&wpos[d], 1);
        colsrc[slot] = ei[e];            // store src node id
    }
}

// ------------------------------------------------- fused head weight (wl@wl2)
__global__ void fuse_wl(const float* __restrict__ wl, const float* __restrict__ bl,
                        const float* __restrict__ wl2, const float* __restrict__ bl2,
                        float* __restrict__ wf, float* __restrict__ bf) {
    int t = threadIdx.x;                 // 128 threads
    float s = 0.f;
    for (int j = 0; j < 128; ++j) s += wl[t * 128 + j] * wl2[j];
    wf[t] = s;
    if (t == 0) {
        float s2 = 0.f;
        for (int j = 0; j < 128; ++j) s2 += bl[j] * wl2[j];
        bf[0] = s2 + bl2[0];
    }
}

// ---------------------------------------------------------------- fused GEMM
// O[sel] = F @ W[sel] + b[sel], sel in {Q,K,V,skip}; F is (NNODES x 128).
// One block owns 64 rows, loops over all 8 (sel, col-half) slices, restaging
// only B (weights L2-resident). A staged once -> F read once from HBM.
// Per-thread state: 4 named float4 accs (~35 VGPR). No spill possible.
#define RF(ACC, AV)                                                           \
    ACC.x = fmaf((AV), b4.x, ACC.x); ACC.y = fmaf((AV), b4.y, ACC.y);         \
    ACC.z = fmaf((AV), b4.z, ACC.z); ACC.w = fmaf((AV), b4.w, ACC.w);

__global__ __launch_bounds__(256)
void gemm_qkvs(const float* __restrict__ F,
               const float* __restrict__ wq, const float* __restrict__ bq,
               const float* __restrict__ wk, const float* __restrict__ bk,
               const float* __restrict__ wv, const float* __restrict__ bv,
               const float* __restrict__ wsk, const float* __restrict__ bsk,
               float* __restrict__ Q, float* __restrict__ Kp,
               float* __restrict__ V, float* __restrict__ H) {
    __shared__ __align__(16) float As[128][68];   // [k][row], 34.8 KB
    __shared__ __align__(16) float Bs[128][68];   // [k][col], 34.8 KB
    const int t  = threadIdx.x;
    const int m0 = blockIdx.x * 64;

    {   // stage A tile: 64 rows x 128 k, transposed. Each thread: 8 float4.
        const int rl = t >> 2;                   // 0..63
        const int kb = (t & 3) * 32;             // 0,32,64,96
        const int gr = min(m0 + rl, NNODES - 1); // clamp tail (stores guarded)
#pragma unroll
        for (int p = 0; p < 8; ++p) {
            const float4 v = *(const float4*)&F[(size_t)gr * 128 + kb + p * 4];
            As[kb + p * 4 + 0][rl] = v.x;
            As[kb + p * 4 + 1][rl] = v.y;
            As[kb + p * 4 + 2][rl] = v.z;
            As[kb + p * 4 + 3][rl] = v.w;
        }
    }
    const int tr = (t >> 4) * 4;                 // acc row base 0..60
    const int tc = (t & 15) * 4;                 // acc col base 0..60
    const int kB = t >> 3;                       // B-stage row 0..31 (+p*32)
    const int cB = (t & 7) * 8;                  // B-stage col

    for (int sl = 0; sl < 8; ++sl) {
        const int sel = sl >> 1;
        const int c0  = (sl & 1) * 64;
        const float* W    = sel == 0 ? wq : sel == 1 ? wk : sel == 2 ? wv : wsk;
        const float* bias = sel == 0 ? bq : sel == 1 ? bk : sel == 2 ? bv : bsk;
        float* O          = sel == 0 ? Q  : sel == 1 ? Kp : sel == 2 ? V  : H;

#pragma unroll
        for (int p = 0; p < 4; ++p) {            // stage B slice 128 x 64
            const int k = kB + p * 32;
            *(float4*)&Bs[k][cB]     = *(const float4*)&W[k * 128 + c0 + cB];
            *(float4*)&Bs[k][cB + 4] = *(const float4*)&W[k * 128 + c0 + cB + 4];
        }
        __syncthreads();                         // Bs ready (and As on sl==0)

        float4 a0 = make_float4(0.f, 0.f, 0.f, 0.f);
        float4 a1 = a0, a2 = a0, a3 = a0;
#pragma unroll 4
        for (int k = 0; k < 128; ++k) {
            const float4 b4 = *(const float4*)&Bs[k][tc];
            const float4 av = *(const float4*)&As[k][tr];
            RF(a0, av.x) RF(a1, av.y) RF(a2, av.z) RF(a3, av.w)
        }
        __syncthreads();                         // readers done before restage

        const float4 bias4 = *(const float4*)&bias[c0 + tc];
#define STORE_ROW(I, ACC)                                                     \
        {                                                                     \
            const int gr = m0 + tr + (I);                                     \
            if (gr < NNODES) {                                                \
                const float4 o = make_float4(ACC.x + bias4.x, ACC.y + bias4.y,\
                                             ACC.z + bias4.z, ACC.w + bias4.w);\
                *(float4*)&O[(size_t)gr * 128 + c0 + tc] = o;                 \
            }                                                                 \
        }
        STORE_ROW(0, a0) STORE_ROW(1, a1) STORE_ROW(2, a2) STORE_ROW(3, a3)
#undef STORE_ROW
    }
}

// --------------------------------------------- per-dst-node online softmax agg
// block = 128 threads (channel c = tid; head = c>>5), one block per node.
// H holds the skip term on entry. FUSE_HEAD=false: H <- relu(skip + msg).
// FUSE_HEAD=true (layer 2): write r[n] = dot(relu(skip+msg), wf) instead --
// feeds graph_pool, saves the 25.6 MB H2 round-trip and the per-node pass.
template <bool FUSE_HEAD>
__global__ __launch_bounds__(128)
void attn_agg(const float* __restrict__ Q, const float* __restrict__ K,
              const float* __restrict__ V, float* __restrict__ H,
              const int* __restrict__ rowptr, const int* __restrict__ colsrc,
              const float* __restrict__ wf, float* __restrict__ r) {
    const int n = blockIdx.x;
    const int c = threadIdx.x;
    const float q = Q[n * 128 + c] * 0.17677669529663687f;   // 1/sqrt(32) folded
    const int beg = rowptr[n], end = rowptr[n + 1];
    float m = -INFINITY, s = 0.f, acc = 0.f;
    float kN = 0.f, vN = 0.f;
    if (beg < end) {
        int s0 = colsrc[beg];
        kN = K[s0 * 128 + c];
        vN = V[s0 * 128 + c];
    }
    for (int i = beg; i < end; ++i) {
        float kc = kN, vc = vN;
        if (i + 1 < end) {               // prefetch next edge's K/V
            int s2 = colsrc[i + 1];
            kN = K[s2 * 128 + c];
            vN = V[s2 * 128 + c];
        }
        float p = q * kc;
#pragma unroll
        for (int off = 16; off > 0; off >>= 1) p += __shfl_xor(p, off, 32);
        float nm = fmaxf(m, p);
        float sc = __expf(m - nm);
        float w  = __expf(p - nm);
        s   = s * sc + w;
        acc = acc * sc + w * vc;
        m = nm;
    }
    float out = H[n * 128 + c];
    if (end > beg) out += acc / s;
    out = fmaxf(out, 0.f);
    if (!FUSE_HEAD) {
        H[n * 128 + c] = out;
    } else {
        float val = out * wf[c];
#pragma unroll
        for (int off = 32; off > 0; off >>= 1) val += __shfl_xor(val, off, 64);
        __shared__ float pw[2];
        if ((c & 63) == 0) pw[c >> 6] = val;
        __syncthreads();
        if (c == 0) r[n] = pw[0] + pw[1];
    }
}

// ----------------------------------------------- per-graph mean (batch sorted)
// One block per graph: binary-search the contiguous node range, block-reduce.
// Replaces the atomicAdd pool (round-3 top kernel: 295 us of pure atomic
// serialization on 128 addresses).
__global__ __launch_bounds__(256)
void graph_pool(const float* __restrict__ r, const int* __restrict__ batch,
                const float* __restrict__ bf, float* __restrict__ out) {
    const int g = blockIdx.x;
    const int t = threadIdx.x;
    // lower_bound(batch, g) and lower_bound(batch, g+1), redundant per thread
    int lo = 0, hi = NNODES;
    while (lo < hi) { int mid = (lo + hi) >> 1; if (batch[mid] < g) lo = mid + 1; else hi = mid; }
    const int beg = lo;
    lo = beg; hi = NNODES;
    while (lo < hi) { int mid = (lo + hi) >> 1; if (batch[mid] < g + 1) lo = mid + 1; else hi = mid; }
    const int end = lo;

    float s = 0.f;
    for (int i = beg + t; i < end; i += 256) s += r[i];
#pragma unroll
    for (int off = 32; off > 0; off >>= 1) s += __shfl_xor(s, off, 64);
    __shared__ float pw[4];
    if ((t & 63) == 0) pw[t >> 6] = s;
    __syncthreads();
    if (t == 0) {
        const float cnt = (float)(end - beg);
        const float tot = pw[0] + pw[1] + pw[2] + pw[3] + cnt * bf[0];
        out[g] = tot / fmaxf(cnt, 1.f);
    }
}

// ---------------------------------------------------------------------- launch
extern "C" void kernel_launch(void* const* d_in, const int* in_sizes, int n_in,
                              void* d_out, int out_size, void* d_ws, size_t ws_size,
                              hipStream_t stream) {
    const float* x     = (const float*)d_in[0];
    const int*   ei    = (const int*)d_in[1];
    const int*   batch = (const int*)d_in[2];
    const float* wq1 = (const float*)d_in[3];  const float* bq1 = (const float*)d_in[4];
    const float* wk1 = (const float*)d_in[5];  const float* bk1 = (const float*)d_in[6];
    const float* wv1 = (const float*)d_in[7];  const float* bv1 = (const float*)d_in[8];
    const float* ws1 = (const float*)d_in[9];  const float* bs1 = (const float*)d_in[10];
    const float* wq2 = (const float*)d_in[11]; const float* bq2 = (const float*)d_in[12];
    const float* wk2 = (const float*)d_in[13]; const float* bk2 = (const float*)d_in[14];
    const float* wv2 = (const float*)d_in[15]; const float* bv2 = (const float*)d_in[16];
    const float* ws2 = (const float*)d_in[17]; const float* bs2 = (const float*)d_in[18];
    const float* wl  = (const float*)d_in[19]; const float* bl  = (const float*)d_in[20];
    const float* wl2 = (const float*)d_in[21]; const float* bl2 = (const float*)d_in[22];

    char* wsb = (char*)d_ws;
    size_t off = 0;
    auto carve = [&](size_t bytes) -> void* {
        void* p = wsb + off;
        off = (off + bytes + 255) & ~(size_t)255;
        return p;
    };
    const size_t NM = (size_t)NNODES * 128 * sizeof(float);   // 25.6 MB
    float* Q      = (float*)carve(NM);
    float* K      = (float*)carve(NM);
    float* V      = (float*)carve(NM);
    float* H1     = (float*)carve(NM);
    float* H2     = (float*)carve(NM);
    int*   rowptr = (int*)carve((NNODES + 1) * sizeof(int));
    int*   wpos   = (int*)carve(NNODES * sizeof(int));
    int*   cnt    = (int*)carve(NNODES * sizeof(int));
    int*   colsrc = (int*)carve(NEDGES * sizeof(int));
    float* wf     = (float*)carve(129 * sizeof(float));  // 128 fused weights + bias
    float* bf     = wf + 128;
    float* nodeval = (float*)carve(NNODES * sizeof(float));

    hipMemsetAsync(cnt, 0, NNODES * sizeof(int), stream);

    count_edges<<<(NEDGES + 255) / 256, 256, 0, stream>>>(ei, cnt);
    scan_counts<<<1, 256, 0, stream>>>(cnt, rowptr, wpos);
    fill_csr<<<(NEDGES + 255) / 256, 256, 0, stream>>>(ei, wpos, colsrc);
    fuse_wl<<<1, 128, 0, stream>>>(wl, bl, wl2, bl2, wf, bf);

    const int ggrid = (NNODES + 63) / 64;      // 782 blocks, 8 slices each
    // layer 1
    gemm_qkvs<<<ggrid, 256, 0, stream>>>(x, wq1, bq1, wk1, bk1, wv1, bv1, ws1, bs1,
                                         Q, K, V, H1);
    attn_agg<false><<<NNODES, 128, 0, stream>>>(Q, K, V, H1, rowptr, colsrc,
                                                nullptr, nullptr);
    // layer 2
    gemm_qkvs<<<ggrid, 256, 0, stream>>>(H1, wq2, bq2, wk2, bk2, wv2, bv2, ws2, bs2,
                                         Q, K, V, H2);
    attn_agg<true><<<NNODES, 128, 0, stream>>>(Q, K, V, H2, rowptr, colsrc,
                                               wf, nodeval);
    // per-graph mean over sorted batch ranges (no atomics)
    graph_pool<<<NGRAPHS, 256, 0, stream>>>(nodeval, batch, bf, (float*)d_out);
}

// Round 5
// 613.294 us; speedup vs baseline: 22.0924x; 1.3072x over previous
//
#include <hip/hip_runtime.h>
#include <hip/hip_bf16.h>
#include <math.h>

#define NNODES 50000
#define NEDGES 800000
#define NGRAPHS 128

typedef __attribute__((ext_vector_type(8))) short bf16x8;   // 8 bf16 = 4 VGPR
typedef __attribute__((ext_vector_type(4))) float f32x4;    // MFMA acc

__device__ __forceinline__ unsigned short f2bf(float f) {   // fp32->bf16 RNE
    unsigned int u = __float_as_uint(f);
    return (unsigned short)((u + 0x7FFFu + ((u >> 16) & 1u)) >> 16);
}

// ---------------------------------------------------------------- CSR build
__global__ void count_edges(const int* __restrict__ ei, int* __restrict__ cnt) {
    int e = blockIdx.x * 256 + threadIdx.x;
    if (e < NEDGES) atomicAdd(&cnt[ei[NEDGES + e]], 1);
}

__global__ void scan_counts(const int* __restrict__ cnt, int* __restrict__ rowptr,
                            int* __restrict__ wpos) {
    __shared__ int part[256];
    const int t = threadIdx.x;
    const int CHK = (NNODES + 255) / 256;     // 196
    int lo = t * CHK, hi = min(lo + CHK, NNODES);
    int s = 0;
    for (int i = lo; i < hi; ++i) s += cnt[i];
    part[t] = s;
    __syncthreads();
    for (int off = 1; off < 256; off <<= 1) {
        int v = (t >= off) ? part[t - off] : 0;
        __syncthreads();
        part[t] += v;
        __syncthreads();
    }
    int run = (t == 0) ? 0 : part[t - 1];
    for (int i = lo; i < hi; ++i) { rowptr[i] = run; wpos[i] = run; run += cnt[i]; }
    if (t == 255) rowptr[NNODES] = part[255];
}

__global__ void fill_csr(const int* __restrict__ ei, int* __restrict__ wpos,
                         int* __restrict__ colsrc) {
    int e = blockIdx.x * 256 + threadIdx.x;
    if (e < NEDGES) {
        int d = ei[NEDGES + e];
        int slot = atomicAdd(&wpos[d], 1);
        colsrc[slot] = ei[e];            // store src node id
    }
}

// ------------------------------------------------- fused head weight (wl@wl2)
__global__ void fuse_wl(const float* __restrict__ wl, const float* __restrict__ bl,
                        const float* __restrict__ wl2, const float* __restrict__ bl2,
                        float* __restrict__ wf, float* __restrict__ bf) {
    int t = threadIdx.x;                 // 128 threads
    float s = 0.f;
    for (int j = 0; j < 128; ++j) s += wl[t * 128 + j] * wl2[j];
    wf[t] = s;
    if (t == 0) {
        float s2 = 0.f;
        for (int j = 0; j < 128; ++j) s2 += bl[j] * wl2[j];
        bf[0] = s2 + bl2[0];
    }
}

// ------------------------------------- weight prep: transpose + bf16 convert
// Wt[sel][col][k] bf16 (4 x 128 x 128 = 128 KB). Coalesced W-row reads.
__global__ void prep_w(const float* __restrict__ wq, const float* __restrict__ wk,
                       const float* __restrict__ wv, const float* __restrict__ wsk,
                       unsigned short* __restrict__ Wt) {
    const int sel = blockIdx.y;
    const float* W = sel == 0 ? wq : sel == 1 ? wk : sel == 2 ? wv : wsk;
    const int idx = blockIdx.x * 256 + threadIdx.x;   // 0..16383
    const int col = idx & 127;
    const int k   = idx >> 7;
    Wt[sel * 16384 + col * 128 + k] = f2bf(W[k * 128 + col]);
}

// ------------------------------------------------------------ MFMA fused GEMM
// O[sel] = F @ W[sel] + b[sel] via mfma_f32_16x16x32_bf16 (fp32 accum).
// Block = 256 thr (4 waves) x 128 rows; loops over 8 (sel, col-half) slices.
// A staged once (bf16, [128][136] pad-8: uniform 8 words/bank on frag b128
// reads). B from pre-transposed Wt, restaged per slice (pure 16B copies).
// Frag layouts (m89/m91-verified): A: row=l&15, k=(l>>4)*8+j ; B: col=l&15,
// k=(l>>4)*8+j ; C/D: col=l&15, row=(l>>4)*4+reg. Bias folded into acc init.
__global__ __launch_bounds__(256)
void gemm_qkvs(const float* __restrict__ F, const unsigned short* __restrict__ Wt,
               const float* __restrict__ bq, const float* __restrict__ bk,
               const float* __restrict__ bv, const float* __restrict__ bsk,
               float* __restrict__ Q, float* __restrict__ Kp,
               float* __restrict__ V, float* __restrict__ H) {
    __shared__ __align__(16) unsigned short As[128][136];   // 34.8 KB
    __shared__ __align__(16) unsigned short Bt[64][136];    // 17.4 KB
    const int t    = threadIdx.x;
    const int m0   = blockIdx.x * 128;
    const int lane = t & 63;
    const int w    = t >> 6;            // wave 0..3 -> rows [w*32, w*32+32)
    const int l15  = lane & 15;
    const int lg   = lane >> 4;         // 0..3

    {   // stage A: 128 rows x 128 k, fp32 -> bf16
        const int row = t >> 1;
        const int kh  = (t & 1) * 64;
        const int gr  = min(m0 + row, NNODES - 1);   // tail clamp; stores guarded
        const float* src = &F[(size_t)gr * 128 + kh];
#pragma unroll
        for (int p = 0; p < 16; ++p) {
            const float4 v = *(const float4*)&src[p * 4];
            ushort4 u;
            u.x = f2bf(v.x); u.y = f2bf(v.y); u.z = f2bf(v.z); u.w = f2bf(v.w);
            *(ushort4*)&As[row][kh + p * 4] = u;
        }
    }

    for (int sl = 0; sl < 8; ++sl) {
        const int sel = sl >> 1;
        const int c0  = (sl & 1) * 64;
        const float* bias = sel == 0 ? bq : sel == 1 ? bk : sel == 2 ? bv : bsk;
        float* O          = sel == 0 ? Q  : sel == 1 ? Kp : sel == 2 ? V  : H;

        {   // stage Bt slice: 64 cols x 128 k bf16 (16B vector copies)
            const int col = t >> 2;
            const int kb  = (t & 3) * 32;
            const unsigned short* src = &Wt[sel * 16384 + (c0 + col) * 128 + kb];
#pragma unroll
            for (int p = 0; p < 4; ++p)
                *(uint4*)&Bt[col][kb + p * 8] = *(const uint4*)&src[p * 8];
        }
        __syncthreads();                 // Bt ready (and As on sl==0)

        const float b0 = bias[c0 + l15];
        const float b1 = bias[c0 + 16 + l15];
        const float b2 = bias[c0 + 32 + l15];
        const float b3 = bias[c0 + 48 + l15];
        f32x4 a00 = {b0, b0, b0, b0}, a01 = {b1, b1, b1, b1},
              a02 = {b2, b2, b2, b2}, a03 = {b3, b3, b3, b3};
        f32x4 a10 = a00, a11 = a01, a12 = a02, a13 = a03;
#pragma unroll
        for (int ks = 0; ks < 4; ++ks) {
            const int kof = ks * 32 + lg * 8;
            const bf16x8 af0 = *(const bf16x8*)&As[w * 32 + l15][kof];
            const bf16x8 af1 = *(const bf16x8*)&As[w * 32 + 16 + l15][kof];
            const bf16x8 bf0 = *(const bf16x8*)&Bt[l15][kof];
            const bf16x8 bf1 = *(const bf16x8*)&Bt[16 + l15][kof];
            const bf16x8 bf2 = *(const bf16x8*)&Bt[32 + l15][kof];
            const bf16x8 bf3 = *(const bf16x8*)&Bt[48 + l15][kof];
            a00 = __builtin_amdgcn_mfma_f32_16x16x32_bf16(af0, bf0, a00, 0, 0, 0);
            a01 = __builtin_amdgcn_mfma_f32_16x16x32_bf16(af0, bf1, a01, 0, 0, 0);
            a02 = __builtin_amdgcn_mfma_f32_16x16x32_bf16(af0, bf2, a02, 0, 0, 0);
            a03 = __builtin_amdgcn_mfma_f32_16x16x32_bf16(af0, bf3, a03, 0, 0, 0);
            a10 = __builtin_amdgcn_mfma_f32_16x16x32_bf16(af1, bf0, a10, 0, 0, 0);
            a11 = __builtin_amdgcn_mfma_f32_16x16x32_bf16(af1, bf1, a11, 0, 0, 0);
            a12 = __builtin_amdgcn_mfma_f32_16x16x32_bf16(af1, bf2, a12, 0, 0, 0);
            a13 = __builtin_amdgcn_mfma_f32_16x16x32_bf16(af1, bf3, a13, 0, 0, 0);
        }
        __syncthreads();                 // readers done before next Bt restage

        const int r0 = m0 + w * 32 + lg * 4;
#define ST(ACC, RT, CT)                                                        \
        _Pragma("unroll")                                                      \
        for (int i = 0; i < 4; ++i) {                                          \
            const int gr = r0 + (RT) * 16 + i;                                 \
            if (gr < NNODES) O[(size_t)gr * 128 + c0 + (CT) * 16 + l15] = ACC[i]; \
        }
        ST(a00, 0, 0) ST(a01, 0, 1) ST(a02, 0, 2) ST(a03, 0, 3)
        ST(a10, 1, 0) ST(a11, 1, 1) ST(a12, 1, 2) ST(a13, 1, 3)
#undef ST
    }
}

// --------------------------------------------- per-dst-node online softmax agg
// block = 128 threads (channel c = tid; head = c>>5), one block per node.
// H holds the skip term on entry. FUSE_HEAD=false: H <- relu(skip + msg).
// FUSE_HEAD=true (layer 2): write r[n] = dot(relu(skip+msg), wf) instead.
template <bool FUSE_HEAD>
__global__ __launch_bounds__(128)
void attn_agg(const float* __restrict__ Q, const float* __restrict__ K,
              const float* __restrict__ V, float* __restrict__ H,
              const int* __restrict__ rowptr, const int* __restrict__ colsrc,
              const float* __restrict__ wf, float* __restrict__ r) {
    const int n = blockIdx.x;
    const int c = threadIdx.x;
    const float q = Q[n * 128 + c] * 0.17677669529663687f;   // 1/sqrt(32) folded
    const int beg = rowptr[n], end = rowptr[n + 1];
    float m = -INFINITY, s = 0.f, acc = 0.f;
    float kN = 0.f, vN = 0.f;
    if (beg < end) {
        int s0 = colsrc[beg];
        kN = K[s0 * 128 + c];
        vN = V[s0 * 128 + c];
    }
    for (int i = beg; i < end; ++i) {
        float kc = kN, vc = vN;
        if (i + 1 < end) {               // prefetch next edge's K/V
            int s2 = colsrc[i + 1];
            kN = K[s2 * 128 + c];
            vN = V[s2 * 128 + c];
        }
        float p = q * kc;
#pragma unroll
        for (int off = 16; off > 0; off >>= 1) p += __shfl_xor(p, off, 32);
        float nm = fmaxf(m, p);
        float sc = __expf(m - nm);
        float w  = __expf(p - nm);
        s   = s * sc + w;
        acc = acc * sc + w * vc;
        m = nm;
    }
    float out = H[n * 128 + c];
    if (end > beg) out += acc / s;
    out = fmaxf(out, 0.f);
    if (!FUSE_HEAD) {
        H[n * 128 + c] = out;
    } else {
        float val = out * wf[c];
#pragma unroll
        for (int off = 32; off > 0; off >>= 1) val += __shfl_xor(val, off, 64);
        __shared__ float pw[2];
        if ((c & 63) == 0) pw[c >> 6] = val;
        __syncthreads();
        if (c == 0) r[n] = pw[0] + pw[1];
    }
}

// ----------------------------------------------- per-graph mean (batch sorted)
__global__ __launch_bounds__(256)
void graph_pool(const float* __restrict__ r, const int* __restrict__ batch,
                const float* __restrict__ bf, float* __restrict__ out) {
    const int g = blockIdx.x;
    const int t = threadIdx.x;
    int lo = 0, hi = NNODES;
    while (lo < hi) { int mid = (lo + hi) >> 1; if (batch[mid] < g) lo = mid + 1; else hi = mid; }
    const int beg = lo;
    lo = beg; hi = NNODES;
    while (lo < hi) { int mid = (lo + hi) >> 1; if (batch[mid] < g + 1) lo = mid + 1; else hi = mid; }
    const int end = lo;

    float s = 0.f;
    for (int i = beg + t; i < end; i += 256) s += r[i];
#pragma unroll
    for (int off = 32; off > 0; off >>= 1) s += __shfl_xor(s, off, 64);
    __shared__ float pw[4];
    if ((t & 63) == 0) pw[t >> 6] = s;
    __syncthreads();
    if (t == 0) {
        const float cnt = (float)(end - beg);
        const float tot = pw[0] + pw[1] + pw[2] + pw[3] + cnt * bf[0];
        out[g] = tot / fmaxf(cnt, 1.f);
    }
}

// ---------------------------------------------------------------------- launch
extern "C" void kernel_launch(void* const* d_in, const int* in_sizes, int n_in,
                              void* d_out, int out_size, void* d_ws, size_t ws_size,
                              hipStream_t stream) {
    const float* x     = (const float*)d_in[0];
    const int*   ei    = (const int*)d_in[1];
    const int*   batch = (const int*)d_in[2];
    const float* wq1 = (const float*)d_in[3];  const float* bq1 = (const float*)d_in[4];
    const float* wk1 = (const float*)d_in[5];  const float* bk1 = (const float*)d_in[6];
    const float* wv1 = (const float*)d_in[7];  const float* bv1 = (const float*)d_in[8];
    const float* ws1 = (const float*)d_in[9];  const float* bs1 = (const float*)d_in[10];
    const float* wq2 = (const float*)d_in[11]; const float* bq2 = (const float*)d_in[12];
    const float* wk2 = (const float*)d_in[13]; const float* bk2 = (const float*)d_in[14];
    const float* wv2 = (const float*)d_in[15]; const float* bv2 = (const float*)d_in[16];
    const float* ws2 = (const float*)d_in[17]; const float* bs2 = (const float*)d_in[18];
    const float* wl  = (const float*)d_in[19]; const float* bl  = (const float*)d_in[20];
    const float* wl2 = (const float*)d_in[21]; const float* bl2 = (const float*)d_in[22];

    char* wsb = (char*)d_ws;
    size_t off = 0;
    auto carve = [&](size_t bytes) -> void* {
        void* p = wsb + off;
        off = (off + bytes + 255) & ~(size_t)255;
        return p;
    };
    const size_t NM = (size_t)NNODES * 128 * sizeof(float);   // 25.6 MB
    float* Q      = (float*)carve(NM);
    float* K      = (float*)carve(NM);
    float* V      = (float*)carve(NM);
    float* H1     = (float*)carve(NM);
    float* H2     = (float*)carve(NM);
    int*   rowptr = (int*)carve((NNODES + 1) * sizeof(int));
    int*   wpos   = (int*)carve(NNODES * sizeof(int));
    int*   cnt    = (int*)carve(NNODES * sizeof(int));
    int*   colsrc = (int*)carve(NEDGES * sizeof(int));
    float* wf     = (float*)carve(129 * sizeof(float));
    float* bf     = wf + 128;
    float* nodeval = (float*)carve(NNODES * sizeof(float));
    unsigned short* Wt1 = (unsigned short*)carve(65536 * sizeof(unsigned short));
    unsigned short* Wt2 = (unsigned short*)carve(65536 * sizeof(unsigned short));

    hipMemsetAsync(cnt, 0, NNODES * sizeof(int), stream);

    count_edges<<<(NEDGES + 255) / 256, 256, 0, stream>>>(ei, cnt);
    scan_counts<<<1, 256, 0, stream>>>(cnt, rowptr, wpos);
    fill_csr<<<(NEDGES + 255) / 256, 256, 0, stream>>>(ei, wpos, colsrc);
    fuse_wl<<<1, 128, 0, stream>>>(wl, bl, wl2, bl2, wf, bf);
    prep_w<<<dim3(64, 4), 256, 0, stream>>>(wq1, wk1, wv1, ws1, Wt1);
    prep_w<<<dim3(64, 4), 256, 0, stream>>>(wq2, wk2, wv2, ws2, Wt2);

    const int ggrid = (NNODES + 127) / 128;    // 391 blocks
    // layer 1
    gemm_qkvs<<<ggrid, 256, 0, stream>>>(x, Wt1, bq1, bk1, bv1, bs1, Q, K, V, H1);
    attn_agg<false><<<NNODES, 128, 0, stream>>>(Q, K, V, H1, rowptr, colsrc,
                                                nullptr, nullptr);
    // layer 2
    gemm_qkvs<<<ggrid, 256, 0, stream>>>(H1, Wt2, bq2, bk2, bv2, bs2, Q, K, V, H2);
    attn_agg<true><<<NNODES, 128, 0, stream>>>(Q, K, V, H2, rowptr, colsrc,
                                               wf, nodeval);
    // per-graph mean over sorted batch ranges (no atomics)
    graph_pool<<<NGRAPHS, 256, 0, stream>>>(nodeval, batch, bf, (float*)d_out);
}

// Round 6
// 561.835 us; speedup vs baseline: 24.1159x; 1.0916x over previous
//
#include <hip/hip_runtime.h>
#include <hip/hip_bf16.h>
#include <math.h>

#define NNODES 50000
#define NEDGES 800000
#define NGRAPHS 128

typedef __attribute__((ext_vector_type(8))) short bf16x8;   // 8 bf16 = 4 VGPR
typedef __attribute__((ext_vector_type(4))) float f32x4;    // MFMA acc

__device__ __forceinline__ unsigned short f2bf(float f) {   // fp32->bf16 RNE
    unsigned int u = __float_as_uint(f);
    return (unsigned short)((u + 0x7FFFu + ((u >> 16) & 1u)) >> 16);
}
__device__ __forceinline__ float2 bf2f2(unsigned int u) {   // bf16x2 -> 2x fp32
    float2 f;
    f.x = __uint_as_float(u << 16);
    f.y = __uint_as_float(u & 0xFFFF0000u);
    return f;
}

// ---------------------------------------------------------------- CSR build
__global__ void count_edges(const int* __restrict__ ei, int* __restrict__ cnt) {
    int e = blockIdx.x * 256 + threadIdx.x;
    if (e < NEDGES) atomicAdd(&cnt[ei[NEDGES + e]], 1);
}

__global__ void scan_counts(const int* __restrict__ cnt, int* __restrict__ rowptr,
                            int* __restrict__ wpos) {
    __shared__ int part[256];
    const int t = threadIdx.x;
    const int CHK = (NNODES + 255) / 256;     // 196
    int lo = t * CHK, hi = min(lo + CHK, NNODES);
    int s = 0;
    for (int i = lo; i < hi; ++i) s += cnt[i];
    part[t] = s;
    __syncthreads();
    for (int off = 1; off < 256; off <<= 1) {
        int v = (t >= off) ? part[t - off] : 0;
        __syncthreads();
        part[t] += v;
        __syncthreads();
    }
    int run = (t == 0) ? 0 : part[t - 1];
    for (int i = lo; i < hi; ++i) { rowptr[i] = run; wpos[i] = run; run += cnt[i]; }
    if (t == 255) rowptr[NNODES] = part[255];
}

__global__ void fill_csr(const int* __restrict__ ei, int* __restrict__ wpos,
                         int* __restrict__ colsrc) {
    int e = blockIdx.x * 256 + threadIdx.x;
    if (e < NEDGES) {
        int d = ei[NEDGES + e];
        int slot = atomicAdd(&wpos[d], 1);
        colsrc[slot] = ei[e];            // store src node id
    }
}

// ------------------------------------------------- fused head weight (wl@wl2)
__global__ void fuse_wl(const float* __restrict__ wl, const float* __restrict__ bl,
                        const float* __restrict__ wl2, const float* __restrict__ bl2,
                        float* __restrict__ wf, float* __restrict__ bf) {
    int t = threadIdx.x;                 // 128 threads
    float s = 0.f;
    for (int j = 0; j < 128; ++j) s += wl[t * 128 + j] * wl2[j];
    wf[t] = s;
    if (t == 0) {
        float s2 = 0.f;
        for (int j = 0; j < 128; ++j) s2 += bl[j] * wl2[j];
        bf[0] = s2 + bl2[0];
    }
}

// ------------------------------------- weight prep: transpose + bf16 convert
__global__ void prep_w(const float* __restrict__ wq, const float* __restrict__ wk,
                       const float* __restrict__ wv, const float* __restrict__ wsk,
                       unsigned short* __restrict__ Wt) {
    const int sel = blockIdx.y;
    const float* W = sel == 0 ? wq : sel == 1 ? wk : sel == 2 ? wv : wsk;
    const int idx = blockIdx.x * 256 + threadIdx.x;   // 0..16383
    const int col = idx & 127;
    const int k   = idx >> 7;
    Wt[sel * 16384 + col * 128 + k] = f2bf(W[k * 128 + col]);
}

// ------------------------------------------------------------ MFMA fused GEMM
// O[sel] = F @ W[sel] + b[sel] via mfma_f32_16x16x32_bf16 (fp32 accum).
// K output (sel==1) is stored as bf16 (attn gathers it at half the bytes).
__global__ __launch_bounds__(256)
void gemm_qkvs(const float* __restrict__ F, const unsigned short* __restrict__ Wt,
               const float* __restrict__ bq, const float* __restrict__ bk,
               const float* __restrict__ bv, const float* __restrict__ bsk,
               float* __restrict__ Q, unsigned short* __restrict__ Kb,
               float* __restrict__ V, float* __restrict__ H) {
    __shared__ __align__(16) unsigned short As[128][136];   // 34.8 KB
    __shared__ __align__(16) unsigned short Bt[64][136];    // 17.4 KB
    const int t    = threadIdx.x;
    const int m0   = blockIdx.x * 128;
    const int lane = t & 63;
    const int w    = t >> 6;            // wave 0..3 -> rows [w*32, w*32+32)
    const int l15  = lane & 15;
    const int lg   = lane >> 4;         // 0..3

    {   // stage A: 128 rows x 128 k, fp32 -> bf16
        const int row = t >> 1;
        const int kh  = (t & 1) * 64;
        const int gr  = min(m0 + row, NNODES - 1);   // tail clamp; stores guarded
        const float* src = &F[(size_t)gr * 128 + kh];
#pragma unroll
        for (int p = 0; p < 16; ++p) {
            const float4 v = *(const float4*)&src[p * 4];
            ushort4 u;
            u.x = f2bf(v.x); u.y = f2bf(v.y); u.z = f2bf(v.z); u.w = f2bf(v.w);
            *(ushort4*)&As[row][kh + p * 4] = u;
        }
    }

    for (int sl = 0; sl < 8; ++sl) {
        const int sel = sl >> 1;
        const int c0  = (sl & 1) * 64;
        const float* bias = sel == 0 ? bq : sel == 1 ? bk : sel == 2 ? bv : bsk;

        {   // stage Bt slice: 64 cols x 128 k bf16 (16B vector copies)
            const int col = t >> 2;
            const int kb  = (t & 3) * 32;
            const unsigned short* src = &Wt[sel * 16384 + (c0 + col) * 128 + kb];
#pragma unroll
            for (int p = 0; p < 4; ++p)
                *(uint4*)&Bt[col][kb + p * 8] = *(const uint4*)&src[p * 8];
        }
        __syncthreads();                 // Bt ready (and As on sl==0)

        const float b0 = bias[c0 + l15];
        const float b1 = bias[c0 + 16 + l15];
        const float b2 = bias[c0 + 32 + l15];
        const float b3 = bias[c0 + 48 + l15];
        f32x4 a00 = {b0, b0, b0, b0}, a01 = {b1, b1, b1, b1},
              a02 = {b2, b2, b2, b2}, a03 = {b3, b3, b3, b3};
        f32x4 a10 = a00, a11 = a01, a12 = a02, a13 = a03;
#pragma unroll
        for (int ks = 0; ks < 4; ++ks) {
            const int kof = ks * 32 + lg * 8;
            const bf16x8 af0 = *(const bf16x8*)&As[w * 32 + l15][kof];
            const bf16x8 af1 = *(const bf16x8*)&As[w * 32 + 16 + l15][kof];
            const bf16x8 bf0 = *(const bf16x8*)&Bt[l15][kof];
            const bf16x8 bf1 = *(const bf16x8*)&Bt[16 + l15][kof];
            const bf16x8 bf2 = *(const bf16x8*)&Bt[32 + l15][kof];
            const bf16x8 bf3 = *(const bf16x8*)&Bt[48 + l15][kof];
            a00 = __builtin_amdgcn_mfma_f32_16x16x32_bf16(af0, bf0, a00, 0, 0, 0);
            a01 = __builtin_amdgcn_mfma_f32_16x16x32_bf16(af0, bf1, a01, 0, 0, 0);
            a02 = __builtin_amdgcn_mfma_f32_16x16x32_bf16(af0, bf2, a02, 0, 0, 0);
            a03 = __builtin_amdgcn_mfma_f32_16x16x32_bf16(af0, bf3, a03, 0, 0, 0);
            a10 = __builtin_amdgcn_mfma_f32_16x16x32_bf16(af1, bf0, a10, 0, 0, 0);
            a11 = __builtin_amdgcn_mfma_f32_16x16x32_bf16(af1, bf1, a11, 0, 0, 0);
            a12 = __builtin_amdgcn_mfma_f32_16x16x32_bf16(af1, bf2, a12, 0, 0, 0);
            a13 = __builtin_amdgcn_mfma_f32_16x16x32_bf16(af1, bf3, a13, 0, 0, 0);
        }
        __syncthreads();                 // readers done before next Bt restage

        const int r0 = m0 + w * 32 + lg * 4;
        if (sel == 1) {                  // K -> bf16 store
#define STB(ACC, RT, CT)                                                       \
            _Pragma("unroll")                                                  \
            for (int i = 0; i < 4; ++i) {                                      \
                const int gr = r0 + (RT) * 16 + i;                             \
                if (gr < NNODES)                                               \
                    Kb[(size_t)gr * 128 + c0 + (CT) * 16 + l15] = f2bf(ACC[i]);\
            }
            STB(a00, 0, 0) STB(a01, 0, 1) STB(a02, 0, 2) STB(a03, 0, 3)
            STB(a10, 1, 0) STB(a11, 1, 1) STB(a12, 1, 2) STB(a13, 1, 3)
#undef STB
        } else {
            float* O = sel == 0 ? Q : sel == 2 ? V : H;
#define ST(ACC, RT, CT)                                                        \
            _Pragma("unroll")                                                  \
            for (int i = 0; i < 4; ++i) {                                      \
                const int gr = r0 + (RT) * 16 + i;                             \
                if (gr < NNODES)                                               \
                    O[(size_t)gr * 128 + c0 + (CT) * 16 + l15] = ACC[i];       \
            }
            ST(a00, 0, 0) ST(a01, 0, 1) ST(a02, 0, 2) ST(a03, 0, 3)
            ST(a10, 1, 0) ST(a11, 1, 1) ST(a12, 1, 2) ST(a13, 1, 3)
#undef ST
        }
    }
}

// --------------------------------------------- per-dst-node online softmax agg
// One WAVE per node (2 nodes per 128-thr block, no cross-wave sync). Lane l
// owns channels (c, c+1) of head l>>4. K gathered bf16 (256 B/row), V fp32.
// Pair-unrolled online softmax; up to 4 gather rows in flight per wave.
// H holds skip on entry. FUSE_HEAD=false: H <- relu(skip+msg).
// FUSE_HEAD=true: r[n] = dot(relu(skip+msg), wf).
template <bool FUSE_HEAD>
__global__ __launch_bounds__(128)
void attn_agg(const float* __restrict__ Q, const unsigned short* __restrict__ Kb,
              const float* __restrict__ V, float* __restrict__ H,
              const int* __restrict__ rowptr, const int* __restrict__ colsrc,
              const float* __restrict__ wf, float* __restrict__ r) {
    const int n = blockIdx.x * 2 + (threadIdx.x >> 6);
    const int l = threadIdx.x & 63;
    const int c = (l >> 4) * 32 + (l & 15) * 2;     // channel pair base
    const float2 q2 = *(const float2*)&Q[(size_t)n * 128 + c];
    const float q0 = q2.x * 0.17677669529663687f;   // 1/sqrt(32) folded
    const float q1 = q2.y * 0.17677669529663687f;
    const int beg = rowptr[n], end = rowptr[n + 1];
    const int cnt = end - beg;

    float m = -INFINITY, s = 0.f, acc0 = 0.f, acc1 = 0.f;
    unsigned kuA = 0, kuB = 0;
    float vA0 = 0.f, vA1 = 0.f, vB0 = 0.f, vB1 = 0.f;
    if (cnt > 0) {
        const int s0 = colsrc[beg];
        kuA = *(const unsigned*)&Kb[(size_t)s0 * 128 + c];
        const float2 v = *(const float2*)&V[(size_t)s0 * 128 + c];
        vA0 = v.x; vA1 = v.y;
    }
    if (cnt > 1) {
        const int s1 = colsrc[beg + 1];
        kuB = *(const unsigned*)&Kb[(size_t)s1 * 128 + c];
        const float2 v = *(const float2*)&V[(size_t)s1 * 128 + c];
        vB0 = v.x; vB1 = v.y;
    }
    int i = beg;
    for (; i + 1 < end; i += 2) {
        const unsigned ka_u = kuA, kb_u = kuB;
        const float va0 = vA0, va1 = vA1, vb0 = vB0, vb1 = vB1;
        if (i + 2 < end) {               // prefetch 2 ahead into slot A
            const int s2 = colsrc[i + 2];
            kuA = *(const unsigned*)&Kb[(size_t)s2 * 128 + c];
            const float2 v = *(const float2*)&V[(size_t)s2 * 128 + c];
            vA0 = v.x; vA1 = v.y;
        }
        if (i + 3 < end) {               // prefetch 3 ahead into slot B
            const int s3 = colsrc[i + 3];
            kuB = *(const unsigned*)&Kb[(size_t)s3 * 128 + c];
            const float2 v = *(const float2*)&V[(size_t)s3 * 128 + c];
            vB0 = v.x; vB1 = v.y;
        }
        const float2 ka = bf2f2(ka_u), kb2 = bf2f2(kb_u);
        float p0 = fmaf(q0, ka.x, q1 * ka.y);
        float p1 = fmaf(q0, kb2.x, q1 * kb2.y);
#pragma unroll
        for (int off = 8; off > 0; off >>= 1) {
            p0 += __shfl_xor(p0, off, 16);
            p1 += __shfl_xor(p1, off, 16);
        }
        const float nm = fmaxf(fmaxf(p0, p1), m);   // v_max3
        const float sc = __expf(m - nm);
        const float w0 = __expf(p0 - nm);
        const float w1 = __expf(p1 - nm);
        s    = fmaf(s, sc, w0 + w1);
        acc0 = fmaf(acc0, sc, fmaf(w0, va0, w1 * vb0));
        acc1 = fmaf(acc1, sc, fmaf(w0, va1, w1 * vb1));
        m = nm;
    }
    if (i < end) {                       // odd tail: edge i sits in slot A
        const float2 ka = bf2f2(kuA);
        float p0 = fmaf(q0, ka.x, q1 * ka.y);
#pragma unroll
        for (int off = 8; off > 0; off >>= 1) p0 += __shfl_xor(p0, off, 16);
        const float nm = fmaxf(p0, m);
        const float sc = __expf(m - nm);
        const float w0 = __expf(p0 - nm);
        s    = fmaf(s, sc, w0);
        acc0 = fmaf(acc0, sc, w0 * vA0);
        acc1 = fmaf(acc1, sc, w0 * vA1);
    }
    const float2 hv = *(const float2*)&H[(size_t)n * 128 + c];
    float o0 = hv.x, o1 = hv.y;
    if (cnt > 0) {
        const float inv = 1.f / s;
        o0 += acc0 * inv;
        o1 += acc1 * inv;
    }
    o0 = fmaxf(o0, 0.f);
    o1 = fmaxf(o1, 0.f);
    if (!FUSE_HEAD) {
        float2 o; o.x = o0; o.y = o1;
        *(float2*)&H[(size_t)n * 128 + c] = o;
    } else {
        float val = fmaf(o0, wf[c], o1 * wf[c + 1]);
#pragma unroll
        for (int off = 32; off > 0; off >>= 1) val += __shfl_xor(val, off, 64);
        if (l == 0) r[n] = val;
    }
}

// ----------------------------------------------- per-graph mean (batch sorted)
__global__ __launch_bounds__(256)
void graph_pool(const float* __restrict__ r, const int* __restrict__ batch,
                const float* __restrict__ bf, float* __restrict__ out) {
    const int g = blockIdx.x;
    const int t = threadIdx.x;
    int lo = 0, hi = NNODES;
    while (lo < hi) { int mid = (lo + hi) >> 1; if (batch[mid] < g) lo = mid + 1; else hi = mid; }
    const int beg = lo;
    lo = beg; hi = NNODES;
    while (lo < hi) { int mid = (lo + hi) >> 1; if (batch[mid] < g + 1) lo = mid + 1; else hi = mid; }
    const int end = lo;

    float s = 0.f;
    for (int i = beg + t; i < end; i += 256) s += r[i];
#pragma unroll
    for (int off = 32; off > 0; off >>= 1) s += __shfl_xor(s, off, 64);
    __shared__ float pw[4];
    if ((t & 63) == 0) pw[t >> 6] = s;
    __syncthreads();
    if (t == 0) {
        const float cnt = (float)(end - beg);
        const float tot = pw[0] + pw[1] + pw[2] + pw[3] + cnt * bf[0];
        out[g] = tot / fmaxf(cnt, 1.f);
    }
}

// ---------------------------------------------------------------------- launch
extern "C" void kernel_launch(void* const* d_in, const int* in_sizes, int n_in,
                              void* d_out, int out_size, void* d_ws, size_t ws_size,
                              hipStream_t stream) {
    const float* x     = (const float*)d_in[0];
    const int*   ei    = (const int*)d_in[1];
    const int*   batch = (const int*)d_in[2];
    const float* wq1 = (const float*)d_in[3];  const float* bq1 = (const float*)d_in[4];
    const float* wk1 = (const float*)d_in[5];  const float* bk1 = (const float*)d_in[6];
    const float* wv1 = (const float*)d_in[7];  const float* bv1 = (const float*)d_in[8];
    const float* ws1 = (const float*)d_in[9];  const float* bs1 = (const float*)d_in[10];
    const float* wq2 = (const float*)d_in[11]; const float* bq2 = (const float*)d_in[12];
    const float* wk2 = (const float*)d_in[13]; const float* bk2 = (const float*)d_in[14];
    const float* wv2 = (const float*)d_in[15]; const float* bv2 = (const float*)d_in[16];
    const float* ws2 = (const float*)d_in[17]; const float* bs2 = (const float*)d_in[18];
    const float* wl  = (const float*)d_in[19]; const float* bl  = (const float*)d_in[20];
    const float* wl2 = (const float*)d_in[21]; const float* bl2 = (const float*)d_in[22];

    char* wsb = (char*)d_ws;
    size_t off = 0;
    auto carve = [&](size_t bytes) -> void* {
        void* p = wsb + off;
        off = (off + bytes + 255) & ~(size_t)255;
        return p;
    };
    const size_t NM = (size_t)NNODES * 128 * sizeof(float);   // 25.6 MB
    float* Q      = (float*)carve(NM);
    unsigned short* Kb = (unsigned short*)carve((size_t)NNODES * 128 * 2);
    float* V      = (float*)carve(NM);
    float* H1     = (float*)carve(NM);
    float* H2     = (float*)carve(NM);
    int*   rowptr = (int*)carve((NNODES + 1) * sizeof(int));
    int*   wpos   = (int*)carve(NNODES * sizeof(int));
    int*   cnt    = (int*)carve(NNODES * sizeof(int));
    int*   colsrc = (int*)carve(NEDGES * sizeof(int));
    float* wf     = (float*)carve(129 * sizeof(float));
    float* bf     = wf + 128;
    float* nodeval = (float*)carve(NNODES * sizeof(float));
    unsigned short* Wt1 = (unsigned short*)carve(65536 * sizeof(unsigned short));
    unsigned short* Wt2 = (unsigned short*)carve(65536 * sizeof(unsigned short));

    hipMemsetAsync(cnt, 0, NNODES * sizeof(int), stream);

    count_edges<<<(NEDGES + 255) / 256, 256, 0, stream>>>(ei, cnt);
    scan_counts<<<1, 256, 0, stream>>>(cnt, rowptr, wpos);
    fill_csr<<<(NEDGES + 255) / 256, 256, 0, stream>>>(ei, wpos, colsrc);
    fuse_wl<<<1, 128, 0, stream>>>(wl, bl, wl2, bl2, wf, bf);
    prep_w<<<dim3(64, 4), 256, 0, stream>>>(wq1, wk1, wv1, ws1, Wt1);
    prep_w<<<dim3(64, 4), 256, 0, stream>>>(wq2, wk2, wv2, ws2, Wt2);

    const int ggrid = (NNODES + 127) / 128;    // 391 blocks
    const int agrid = NNODES / 2;              // 2 nodes (waves) per block
    // layer 1
    gemm_qkvs<<<ggrid, 256, 0, stream>>>(x, Wt1, bq1, bk1, bv1, bs1, Q, Kb, V, H1);
    attn_agg<false><<<agrid, 128, 0, stream>>>(Q, Kb, V, H1, rowptr, colsrc,
                                               nullptr, nullptr);
    // layer 2
    gemm_qkvs<<<ggrid, 256, 0, stream>>>(H1, Wt2, bq2, bk2, bv2, bs2, Q, Kb, V, H2);
    attn_agg<true><<<agrid, 128, 0, stream>>>(Q, Kb, V, H2, rowptr, colsrc,
                                              wf, nodeval);
    // per-graph mean over sorted batch ranges (no atomics)
    graph_pool<<<NGRAPHS, 256, 0, stream>>>(nodeval, batch, bf, (float*)d_out);
}

// Round 7
// 457.573 us; speedup vs baseline: 29.6109x; 1.2279x over previous
//
#include <hip/hip_runtime.h>
#include <hip/hip_bf16.h>
#include <math.h>

#define NNODES 50000
#define NEDGES 800000
#define NGRAPHS 128
#define SCAN_B ((NNODES + 255) / 256)   // 196 scan blocks

typedef __attribute__((ext_vector_type(8))) short bf16x8;   // 8 bf16 = 4 VGPR
typedef __attribute__((ext_vector_type(4))) float f32x4;    // MFMA acc

__device__ __forceinline__ unsigned short f2bf(float f) {   // fp32->bf16 RNE
    unsigned int u = __float_as_uint(f);
    return (unsigned short)((u + 0x7FFFu + ((u >> 16) & 1u)) >> 16);
}
__device__ __forceinline__ float2 bf2f2(unsigned int u) {   // bf16x2 -> 2x fp32
    float2 f;
    f.x = __uint_as_float(u << 16);
    f.y = __uint_as_float(u & 0xFFFF0000u);
    return f;
}

// ---------------------------------------------------------------- CSR build
__global__ void count_edges(const int* __restrict__ ei, int* __restrict__ cnt) {
    int e = blockIdx.x * 256 + threadIdx.x;
    if (e < NEDGES) atomicAdd(&cnt[ei[NEDGES + e]], 1);
}

// 3-pass device-wide exclusive scan (replaces the 122us single-block scan).
__global__ __launch_bounds__(256)
void scan_pass1(const int* __restrict__ cnt, int* __restrict__ bsum) {
    const int t = threadIdx.x;
    const int i = blockIdx.x * 256 + t;
    int v = (i < NNODES) ? cnt[i] : 0;
#pragma unroll
    for (int off = 32; off > 0; off >>= 1) v += __shfl_xor(v, off, 64);
    __shared__ int ws[4];
    if ((t & 63) == 0) ws[t >> 6] = v;
    __syncthreads();
    if (t == 0) bsum[blockIdx.x] = ws[0] + ws[1] + ws[2] + ws[3];
}

__global__ __launch_bounds__(256)
void scan_pass2(const int* __restrict__ bsum, int* __restrict__ boff) {
    const int t = threadIdx.x;
    const int v = (t < SCAN_B) ? bsum[t] : 0;
    __shared__ int a[256];
    a[t] = v;
    __syncthreads();
    for (int off = 1; off < 256; off <<= 1) {
        const int u = (t >= off) ? a[t - off] : 0;
        __syncthreads();
        a[t] += u;
        __syncthreads();
    }
    if (t < SCAN_B) boff[t] = a[t] - v;   // exclusive
}

__global__ __launch_bounds__(256)
void scan_pass3(const int* __restrict__ cnt, const int* __restrict__ boff,
                int* __restrict__ rowptr, int* __restrict__ wpos) {
    const int t = threadIdx.x;
    const int i = blockIdx.x * 256 + t;
    const int v = (i < NNODES) ? cnt[i] : 0;
    __shared__ int a[256];
    a[t] = v;
    __syncthreads();
    for (int off = 1; off < 256; off <<= 1) {
        const int u = (t >= off) ? a[t - off] : 0;
        __syncthreads();
        a[t] += u;
        __syncthreads();
    }
    if (i < NNODES) {
        const int e = boff[blockIdx.x] + a[t] - v;
        rowptr[i] = e;
        wpos[i]   = e;
    }
    if (i == 0) rowptr[NNODES] = NEDGES;
}

__global__ void fill_csr(const int* __restrict__ ei, int* __restrict__ wpos,
                         int* __restrict__ colsrc) {
    int e = blockIdx.x * 256 + threadIdx.x;
    if (e < NEDGES) {
        int d = ei[NEDGES + e];
        int slot = atomicAdd(&wpos[d], 1);
        colsrc[slot] = ei[e];            // store src node id
    }
}

// ------------------------------------------------- fused head weight (wl@wl2)
__global__ void fuse_wl(const float* __restrict__ wl, const float* __restrict__ bl,
                        const float* __restrict__ wl2, const float* __restrict__ bl2,
                        float* __restrict__ wf, float* __restrict__ bf) {
    int t = threadIdx.x;                 // 128 threads
    float s = 0.f;
    for (int j = 0; j < 128; ++j) s += wl[t * 128 + j] * wl2[j];
    wf[t] = s;
    if (t == 0) {
        float s2 = 0.f;
        for (int j = 0; j < 128; ++j) s2 += bl[j] * wl2[j];
        bf[0] = s2 + bl2[0];
    }
}

// ------------------------------------- weight prep: transpose + bf16 convert
__global__ void prep_w(const float* __restrict__ wq, const float* __restrict__ wk,
                       const float* __restrict__ wv, const float* __restrict__ wsk,
                       unsigned short* __restrict__ Wt) {
    const int sel = blockIdx.y;
    const float* W = sel == 0 ? wq : sel == 1 ? wk : sel == 2 ? wv : wsk;
    const int idx = blockIdx.x * 256 + threadIdx.x;   // 0..16383
    const int col = idx & 127;
    const int k   = idx >> 7;
    Wt[sel * 16384 + col * 128 + k] = f2bf(W[k * 128 + col]);
}

// ------------------------------------------------------------ MFMA fused GEMM
// O[sel] = F @ W[sel] + b[sel] via mfma_f32_16x16x32_bf16 (fp32 accum).
// K output (sel==1) is stored as bf16 (attn gathers it at half the bytes).
__global__ __launch_bounds__(256)
void gemm_qkvs(const float* __restrict__ F, const unsigned short* __restrict__ Wt,
               const float* __restrict__ bq, const float* __restrict__ bk,
               const float* __restrict__ bv, const float* __restrict__ bsk,
               float* __restrict__ Q, unsigned short* __restrict__ Kb,
               float* __restrict__ V, float* __restrict__ H) {
    __shared__ __align__(16) unsigned short As[128][136];   // 34.8 KB
    __shared__ __align__(16) unsigned short Bt[64][136];    // 17.4 KB
    const int t    = threadIdx.x;
    const int m0   = blockIdx.x * 128;
    const int lane = t & 63;
    const int w    = t >> 6;            // wave 0..3 -> rows [w*32, w*32+32)
    const int l15  = lane & 15;
    const int lg   = lane >> 4;         // 0..3

    {   // stage A: 128 rows x 128 k, fp32 -> bf16
        const int row = t >> 1;
        const int kh  = (t & 1) * 64;
        const int gr  = min(m0 + row, NNODES - 1);   // tail clamp; stores guarded
        const float* src = &F[(size_t)gr * 128 + kh];
#pragma unroll
        for (int p = 0; p < 16; ++p) {
            const float4 v = *(const float4*)&src[p * 4];
            ushort4 u;
            u.x = f2bf(v.x); u.y = f2bf(v.y); u.z = f2bf(v.z); u.w = f2bf(v.w);
            *(ushort4*)&As[row][kh + p * 4] = u;
        }
    }

    for (int sl = 0; sl < 8; ++sl) {
        const int sel = sl >> 1;
        const int c0  = (sl & 1) * 64;
        const float* bias = sel == 0 ? bq : sel == 1 ? bk : sel == 2 ? bv : bsk;

        {   // stage Bt slice: 64 cols x 128 k bf16 (16B vector copies)
            const int col = t >> 2;
            const int kb  = (t & 3) * 32;
            const unsigned short* src = &Wt[sel * 16384 + (c0 + col) * 128 + kb];
#pragma unroll
            for (int p = 0; p < 4; ++p)
                *(uint4*)&Bt[col][kb + p * 8] = *(const uint4*)&src[p * 8];
        }
        __syncthreads();                 // Bt ready (and As on sl==0)

        const float b0 = bias[c0 + l15];
        const float b1 = bias[c0 + 16 + l15];
        const float b2 = bias[c0 + 32 + l15];
        const float b3 = bias[c0 + 48 + l15];
        f32x4 a00 = {b0, b0, b0, b0}, a01 = {b1, b1, b1, b1},
              a02 = {b2, b2, b2, b2}, a03 = {b3, b3, b3, b3};
        f32x4 a10 = a00, a11 = a01, a12 = a02, a13 = a03;
#pragma unroll
        for (int ks = 0; ks < 4; ++ks) {
            const int kof = ks * 32 + lg * 8;
            const bf16x8 af0 = *(const bf16x8*)&As[w * 32 + l15][kof];
            const bf16x8 af1 = *(const bf16x8*)&As[w * 32 + 16 + l15][kof];
            const bf16x8 bf0 = *(const bf16x8*)&Bt[l15][kof];
            const bf16x8 bf1 = *(const bf16x8*)&Bt[16 + l15][kof];
            const bf16x8 bf2 = *(const bf16x8*)&Bt[32 + l15][kof];
            const bf16x8 bf3 = *(const bf16x8*)&Bt[48 + l15][kof];
            a00 = __builtin_amdgcn_mfma_f32_16x16x32_bf16(af0, bf0, a00, 0, 0, 0);
            a01 = __builtin_amdgcn_mfma_f32_16x16x32_bf16(af0, bf1, a01, 0, 0, 0);
            a02 = __builtin_amdgcn_mfma_f32_16x16x32_bf16(af0, bf2, a02, 0, 0, 0);
            a03 = __builtin_amdgcn_mfma_f32_16x16x32_bf16(af0, bf3, a03, 0, 0, 0);
            a10 = __builtin_amdgcn_mfma_f32_16x16x32_bf16(af1, bf0, a10, 0, 0, 0);
            a11 = __builtin_amdgcn_mfma_f32_16x16x32_bf16(af1, bf1, a11, 0, 0, 0);
            a12 = __builtin_amdgcn_mfma_f32_16x16x32_bf16(af1, bf2, a12, 0, 0, 0);
            a13 = __builtin_amdgcn_mfma_f32_16x16x32_bf16(af1, bf3, a13, 0, 0, 0);
        }
        __syncthreads();                 // readers done before next Bt restage

        const int r0 = m0 + w * 32 + lg * 4;
        if (sel == 1) {                  // K -> bf16 store
#define STB(ACC, RT, CT)                                                       \
            _Pragma("unroll")                                                  \
            for (int i = 0; i < 4; ++i) {                                      \
                const int gr = r0 + (RT) * 16 + i;                             \
                if (gr < NNODES)                                               \
                    Kb[(size_t)gr * 128 + c0 + (CT) * 16 + l15] = f2bf(ACC[i]);\
            }
            STB(a00, 0, 0) STB(a01, 0, 1) STB(a02, 0, 2) STB(a03, 0, 3)
            STB(a10, 1, 0) STB(a11, 1, 1) STB(a12, 1, 2) STB(a13, 1, 3)
#undef STB
        } else {
            float* O = sel == 0 ? Q : sel == 2 ? V : H;
#define ST(ACC, RT, CT)                                                        \
            _Pragma("unroll")                                                  \
            for (int i = 0; i < 4; ++i) {                                      \
                const int gr = r0 + (RT) * 16 + i;                             \
                if (gr < NNODES)                                               \
                    O[(size_t)gr * 128 + c0 + (CT) * 16 + l15] = ACC[i];       \
            }
            ST(a00, 0, 0) ST(a01, 0, 1) ST(a02, 0, 2) ST(a03, 0, 3)
            ST(a10, 1, 0) ST(a11, 1, 1) ST(a12, 1, 2) ST(a13, 1, 3)
#undef ST
        }
    }
}

// --------------------------------------------- per-dst-node online softmax agg
// One WAVE per node (2 nodes per 128-thr block, no cross-wave sync). Lane l
// owns channels (c, c+1) of head l>>4. K gathered bf16 (256 B/row), V fp32.
// Pair-unrolled online softmax; up to 4 gather rows in flight per wave.
// H holds skip on entry. FUSE_HEAD=false: H <- relu(skip+msg).
// FUSE_HEAD=true: r[n] = dot(relu(skip+msg), wf).
template <bool FUSE_HEAD>
__global__ __launch_bounds__(128)
void attn_agg(const float* __restrict__ Q, const unsigned short* __restrict__ Kb,
              const float* __restrict__ V, float* __restrict__ H,
              const int* __restrict__ rowptr, const int* __restrict__ colsrc,
              const float* __restrict__ wf, float* __restrict__ r) {
    const int n = blockIdx.x * 2 + (threadIdx.x >> 6);
    const int l = threadIdx.x & 63;
    const int c = (l >> 4) * 32 + (l & 15) * 2;     // channel pair base
    const float2 q2 = *(const float2*)&Q[(size_t)n * 128 + c];
    const float q0 = q2.x * 0.17677669529663687f;   // 1/sqrt(32) folded
    const float q1 = q2.y * 0.17677669529663687f;
    const int beg = rowptr[n], end = rowptr[n + 1];
    const int cnt = end - beg;

    float m = -INFINITY, s = 0.f, acc0 = 0.f, acc1 = 0.f;
    unsigned kuA = 0, kuB = 0;
    float vA0 = 0.f, vA1 = 0.f, vB0 = 0.f, vB1 = 0.f;
    if (cnt > 0) {
        const int s0 = colsrc[beg];
        kuA = *(const unsigned*)&Kb[(size_t)s0 * 128 + c];
        const float2 v = *(const float2*)&V[(size_t)s0 * 128 + c];
        vA0 = v.x; vA1 = v.y;
    }
    if (cnt > 1) {
        const int s1 = colsrc[beg + 1];
        kuB = *(const unsigned*)&Kb[(size_t)s1 * 128 + c];
        const float2 v = *(const float2*)&V[(size_t)s1 * 128 + c];
        vB0 = v.x; vB1 = v.y;
    }
    int i = beg;
    for (; i + 1 < end; i += 2) {
        const unsigned ka_u = kuA, kb_u = kuB;
        const float va0 = vA0, va1 = vA1, vb0 = vB0, vb1 = vB1;
        if (i + 2 < end) {               // prefetch 2 ahead into slot A
            const int s2 = colsrc[i + 2];
            kuA = *(const unsigned*)&Kb[(size_t)s2 * 128 + c];
            const float2 v = *(const float2*)&V[(size_t)s2 * 128 + c];
            vA0 = v.x; vA1 = v.y;
        }
        if (i + 3 < end) {               // prefetch 3 ahead into slot B
            const int s3 = colsrc[i + 3];
            kuB = *(const unsigned*)&Kb[(size_t)s3 * 128 + c];
            const float2 v = *(const float2*)&V[(size_t)s3 * 128 + c];
            vB0 = v.x; vB1 = v.y;
        }
        const float2 ka = bf2f2(ka_u), kb2 = bf2f2(kb_u);
        float p0 = fmaf(q0, ka.x, q1 * ka.y);
        float p1 = fmaf(q0, kb2.x, q1 * kb2.y);
#pragma unroll
        for (int off = 8; off > 0; off >>= 1) {
            p0 += __shfl_xor(p0, off, 16);
            p1 += __shfl_xor(p1, off, 16);
        }
        const float nm = fmaxf(fmaxf(p0, p1), m);   // v_max3
        const float sc = __expf(m - nm);
        const float w0 = __expf(p0 - nm);
        const float w1 = __expf(p1 - nm);
        s    = fmaf(s, sc, w0 + w1);
        acc0 = fmaf(acc0, sc, fmaf(w0, va0, w1 * vb0));
        acc1 = fmaf(acc1, sc, fmaf(w0, va1, w1 * vb1));
        m = nm;
    }
    if (i < end) {                       // odd tail: edge i sits in slot A
        const float2 ka = bf2f2(kuA);
        float p0 = fmaf(q0, ka.x, q1 * ka.y);
#pragma unroll
        for (int off = 8; off > 0; off >>= 1) p0 += __shfl_xor(p0, off, 16);
        const float nm = fmaxf(p0, m);
        const float sc = __expf(m - nm);
        const float w0 = __expf(p0 - nm);
        s    = fmaf(s, sc, w0);
        acc0 = fmaf(acc0, sc, w0 * vA0);
        acc1 = fmaf(acc1, sc, w0 * vA1);
    }
    const float2 hv = *(const float2*)&H[(size_t)n * 128 + c];
    float o0 = hv.x, o1 = hv.y;
    if (cnt > 0) {
        const float inv = 1.f / s;
        o0 += acc0 * inv;
        o1 += acc1 * inv;
    }
    o0 = fmaxf(o0, 0.f);
    o1 = fmaxf(o1, 0.f);
    if (!FUSE_HEAD) {
        float2 o; o.x = o0; o.y = o1;
        *(float2*)&H[(size_t)n * 128 + c] = o;
    } else {
        float val = fmaf(o0, wf[c], o1 * wf[c + 1]);
#pragma unroll
        for (int off = 32; off > 0; off >>= 1) val += __shfl_xor(val, off, 64);
        if (l == 0) r[n] = val;
    }
}

// ----------------------------------------------- per-graph mean (batch sorted)
__global__ __launch_bounds__(256)
void graph_pool(const float* __restrict__ r, const int* __restrict__ batch,
                const float* __restrict__ bf, float* __restrict__ out) {
    const int g = blockIdx.x;
    const int t = threadIdx.x;
    int lo = 0, hi = NNODES;
    while (lo < hi) { int mid = (lo + hi) >> 1; if (batch[mid] < g) lo = mid + 1; else hi = mid; }
    const int beg = lo;
    lo = beg; hi = NNODES;
    while (lo < hi) { int mid = (lo + hi) >> 1; if (batch[mid] < g + 1) lo = mid + 1; else hi = mid; }
    const int end = lo;

    float s = 0.f;
    for (int i = beg + t; i < end; i += 256) s += r[i];
#pragma unroll
    for (int off = 32; off > 0; off >>= 1) s += __shfl_xor(s, off, 64);
    __shared__ float pw[4];
    if ((t & 63) == 0) pw[t >> 6] = s;
    __syncthreads();
    if (t == 0) {
        const float cnt = (float)(end - beg);
        const float tot = pw[0] + pw[1] + pw[2] + pw[3] + cnt * bf[0];
        out[g] = tot / fmaxf(cnt, 1.f);
    }
}

// ---------------------------------------------------------------------- launch
extern "C" void kernel_launch(void* const* d_in, const int* in_sizes, int n_in,
                              void* d_out, int out_size, void* d_ws, size_t ws_size,
                              hipStream_t stream) {
    const float* x     = (const float*)d_in[0];
    const int*   ei    = (const int*)d_in[1];
    const int*   batch = (const int*)d_in[2];
    const float* wq1 = (const float*)d_in[3];  const float* bq1 = (const float*)d_in[4];
    const float* wk1 = (const float*)d_in[5];  const float* bk1 = (const float*)d_in[6];
    const float* wv1 = (const float*)d_in[7];  const float* bv1 = (const float*)d_in[8];
    const float* ws1 = (const float*)d_in[9];  const float* bs1 = (const float*)d_in[10];
    const float* wq2 = (const float*)d_in[11]; const float* bq2 = (const float*)d_in[12];
    const float* wk2 = (const float*)d_in[13]; const float* bk2 = (const float*)d_in[14];
    const float* wv2 = (const float*)d_in[15]; const float* bv2 = (const float*)d_in[16];
    const float* ws2 = (const float*)d_in[17]; const float* bs2 = (const float*)d_in[18];
    const float* wl  = (const float*)d_in[19]; const float* bl  = (const float*)d_in[20];
    const float* wl2 = (const float*)d_in[21]; const float* bl2 = (const float*)d_in[22];

    char* wsb = (char*)d_ws;
    size_t off = 0;
    auto carve = [&](size_t bytes) -> void* {
        void* p = wsb + off;
        off = (off + bytes + 255) & ~(size_t)255;
        return p;
    };
    const size_t NM = (size_t)NNODES * 128 * sizeof(float);   // 25.6 MB
    float* Q      = (float*)carve(NM);
    unsigned short* Kb = (unsigned short*)carve((size_t)NNODES * 128 * 2);
    float* V      = (float*)carve(NM);
    float* H1     = (float*)carve(NM);
    float* H2     = (float*)carve(NM);
    int*   rowptr = (int*)carve((NNODES + 1) * sizeof(int));
    int*   wpos   = (int*)carve(NNODES * sizeof(int));
    int*   cnt    = (int*)carve(NNODES * sizeof(int));
    int*   colsrc = (int*)carve(NEDGES * sizeof(int));
    int*   bsum   = (int*)carve(256 * sizeof(int));
    int*   boff   = (int*)carve(256 * sizeof(int));
    float* wf     = (float*)carve(129 * sizeof(float));
    float* bf     = wf + 128;
    float* nodeval = (float*)carve(NNODES * sizeof(float));
    unsigned short* Wt1 = (unsigned short*)carve(65536 * sizeof(unsigned short));
    unsigned short* Wt2 = (unsigned short*)carve(65536 * sizeof(unsigned short));

    hipMemsetAsync(cnt, 0, NNODES * sizeof(int), stream);

    count_edges<<<(NEDGES + 255) / 256, 256, 0, stream>>>(ei, cnt);
    scan_pass1<<<SCAN_B, 256, 0, stream>>>(cnt, bsum);
    scan_pass2<<<1, 256, 0, stream>>>(bsum, boff);
    scan_pass3<<<SCAN_B, 256, 0, stream>>>(cnt, boff, rowptr, wpos);
    fill_csr<<<(NEDGES + 255) / 256, 256, 0, stream>>>(ei, wpos, colsrc);
    fuse_wl<<<1, 128, 0, stream>>>(wl, bl, wl2, bl2, wf, bf);
    prep_w<<<dim3(64, 4), 256, 0, stream>>>(wq1, wk1, wv1, ws1, Wt1);
    prep_w<<<dim3(64, 4), 256, 0, stream>>>(wq2, wk2, wv2, ws2, Wt2);

    const int ggrid = (NNODES + 127) / 128;    // 391 blocks
    const int agrid = NNODES / 2;              // 2 nodes (waves) per block
    // layer 1
    gemm_qkvs<<<ggrid, 256, 0, stream>>>(x, Wt1, bq1, bk1, bv1, bs1, Q, Kb, V, H1);
    attn_agg<false><<<agrid, 128, 0, stream>>>(Q, Kb, V, H1, rowptr, colsrc,
                                               nullptr, nullptr);
    // layer 2
    gemm_qkvs<<<ggrid, 256, 0, stream>>>(H1, Wt2, bq2, bk2, bv2, bs2, Q, Kb, V, H2);
    attn_agg<true><<<agrid, 128, 0, stream>>>(Q, Kb, V, H2, rowptr, colsrc,
                                              wf, nodeval);
    // per-graph mean over sorted batch ranges (no atomics)
    graph_pool<<<NGRAPHS, 256, 0, stream>>>(nodeval, batch, bf, (float*)d_out);
}

// Round 8
// 401.643 us; speedup vs baseline: 33.7343x; 1.1393x over previous
//
#include <hip/hip_runtime.h>
#include <hip/hip_bf16.h>
#include <math.h>

#define NNODES 50000
#define NEDGES 800000
#define NGRAPHS 128
#define SCAN_B ((NNODES + 255) / 256)   // 196 scan blocks

typedef __attribute__((ext_vector_type(8))) short bf16x8;   // 8 bf16 = 4 VGPR
typedef __attribute__((ext_vector_type(4))) float f32x4;    // MFMA acc

__device__ __forceinline__ unsigned short f2bf(float f) {   // fp32->bf16 RNE
    unsigned int u = __float_as_uint(f);
    return (unsigned short)((u + 0x7FFFu + ((u >> 16) & 1u)) >> 16);
}
__device__ __forceinline__ float2 bf2f2(unsigned int u) {   // bf16x2 -> 2x fp32
    float2 f;
    f.x = __uint_as_float(u << 16);
    f.y = __uint_as_float(u & 0xFFFF0000u);
    return f;
}

// ---------------------------------------------------------------- CSR build
__global__ void count_edges(const int* __restrict__ ei, int* __restrict__ cnt) {
    int e = blockIdx.x * 256 + threadIdx.x;
    if (e < NEDGES) atomicAdd(&cnt[ei[NEDGES + e]], 1);
}

// 3-pass device-wide exclusive scan
__global__ __launch_bounds__(256)
void scan_pass1(const int* __restrict__ cnt, int* __restrict__ bsum) {
    const int t = threadIdx.x;
    const int i = blockIdx.x * 256 + t;
    int v = (i < NNODES) ? cnt[i] : 0;
#pragma unroll
    for (int off = 32; off > 0; off >>= 1) v += __shfl_xor(v, off, 64);
    __shared__ int ws[4];
    if ((t & 63) == 0) ws[t >> 6] = v;
    __syncthreads();
    if (t == 0) bsum[blockIdx.x] = ws[0] + ws[1] + ws[2] + ws[3];
}

__global__ __launch_bounds__(256)
void scan_pass2(const int* __restrict__ bsum, int* __restrict__ boff) {
    const int t = threadIdx.x;
    const int v = (t < SCAN_B) ? bsum[t] : 0;
    __shared__ int a[256];
    a[t] = v;
    __syncthreads();
    for (int off = 1; off < 256; off <<= 1) {
        const int u = (t >= off) ? a[t - off] : 0;
        __syncthreads();
        a[t] += u;
        __syncthreads();
    }
    if (t < SCAN_B) boff[t] = a[t] - v;   // exclusive
}

__global__ __launch_bounds__(256)
void scan_pass3(const int* __restrict__ cnt, const int* __restrict__ boff,
                int* __restrict__ rowptr, int* __restrict__ wpos) {
    const int t = threadIdx.x;
    const int i = blockIdx.x * 256 + t;
    const int v = (i < NNODES) ? cnt[i] : 0;
    __shared__ int a[256];
    a[t] = v;
    __syncthreads();
    for (int off = 1; off < 256; off <<= 1) {
        const int u = (t >= off) ? a[t - off] : 0;
        __syncthreads();
        a[t] += u;
        __syncthreads();
    }
    if (i < NNODES) {
        const int e = boff[blockIdx.x] + a[t] - v;
        rowptr[i] = e;
        wpos[i]   = e;
    }
    if (i == 0) rowptr[NNODES] = NEDGES;
}

__global__ void fill_csr(const int* __restrict__ ei, int* __restrict__ wpos,
                         int* __restrict__ colsrc) {
    int e = blockIdx.x * 256 + threadIdx.x;
    if (e < NEDGES) {
        int d = ei[NEDGES + e];
        int slot = atomicAdd(&wpos[d], 1);
        colsrc[slot] = ei[e];            // store src node id
    }
}

// ------------------------------------------------- fused head weight (wl@wl2)
__global__ void fuse_wl(const float* __restrict__ wl, const float* __restrict__ bl,
                        const float* __restrict__ wl2, const float* __restrict__ bl2,
                        float* __restrict__ wf, float* __restrict__ bf) {
    int t = threadIdx.x;                 // 128 threads
    float s = 0.f;
    for (int j = 0; j < 128; ++j) s += wl[t * 128 + j] * wl2[j];
    wf[t] = s;
    if (t == 0) {
        float s2 = 0.f;
        for (int j = 0; j < 128; ++j) s2 += bl[j] * wl2[j];
        bf[0] = s2 + bl2[0];
    }
}

// ------------------------------------- weight prep: transpose + bf16 convert
__global__ void prep_w(const float* __restrict__ wq, const float* __restrict__ wk,
                       const float* __restrict__ wv, const float* __restrict__ wsk,
                       unsigned short* __restrict__ Wt) {
    const int sel = blockIdx.y;
    const float* W = sel == 0 ? wq : sel == 1 ? wk : sel == 2 ? wv : wsk;
    const int idx = blockIdx.x * 256 + threadIdx.x;   // 0..16383
    const int col = idx & 127;
    const int k   = idx >> 7;
    Wt[sel * 16384 + col * 128 + k] = f2bf(W[k * 128 + col]);
}

// ------------------------------------------------------------ MFMA fused GEMM
// O[sel] = F @ W[sel] + b[sel] via mfma_f32_16x16x32_bf16 (fp32 accum).
// K and V outputs stored bf16 (attn gathers them at half the bytes).
__global__ __launch_bounds__(256)
void gemm_qkvs(const float* __restrict__ F, const unsigned short* __restrict__ Wt,
               const float* __restrict__ bq, const float* __restrict__ bk,
               const float* __restrict__ bv, const float* __restrict__ bsk,
               float* __restrict__ Q, unsigned short* __restrict__ Kb,
               unsigned short* __restrict__ Vb, float* __restrict__ H) {
    __shared__ __align__(16) unsigned short As[128][136];   // 34.8 KB
    __shared__ __align__(16) unsigned short Bt[64][136];    // 17.4 KB
    const int t    = threadIdx.x;
    const int m0   = blockIdx.x * 128;
    const int lane = t & 63;
    const int w    = t >> 6;            // wave 0..3 -> rows [w*32, w*32+32)
    const int l15  = lane & 15;
    const int lg   = lane >> 4;         // 0..3

    {   // stage A: 128 rows x 128 k, fp32 -> bf16
        const int row = t >> 1;
        const int kh  = (t & 1) * 64;
        const int gr  = min(m0 + row, NNODES - 1);   // tail clamp; stores guarded
        const float* src = &F[(size_t)gr * 128 + kh];
#pragma unroll
        for (int p = 0; p < 16; ++p) {
            const float4 v = *(const float4*)&src[p * 4];
            ushort4 u;
            u.x = f2bf(v.x); u.y = f2bf(v.y); u.z = f2bf(v.z); u.w = f2bf(v.w);
            *(ushort4*)&As[row][kh + p * 4] = u;
        }
    }

    for (int sl = 0; sl < 8; ++sl) {
        const int sel = sl >> 1;
        const int c0  = (sl & 1) * 64;
        const float* bias = sel == 0 ? bq : sel == 1 ? bk : sel == 2 ? bv : bsk;

        {   // stage Bt slice: 64 cols x 128 k bf16 (16B vector copies)
            const int col = t >> 2;
            const int kb  = (t & 3) * 32;
            const unsigned short* src = &Wt[sel * 16384 + (c0 + col) * 128 + kb];
#pragma unroll
            for (int p = 0; p < 4; ++p)
                *(uint4*)&Bt[col][kb + p * 8] = *(const uint4*)&src[p * 8];
        }
        __syncthreads();                 // Bt ready (and As on sl==0)

        const float b0 = bias[c0 + l15];
        const float b1 = bias[c0 + 16 + l15];
        const float b2 = bias[c0 + 32 + l15];
        const float b3 = bias[c0 + 48 + l15];
        f32x4 a00 = {b0, b0, b0, b0}, a01 = {b1, b1, b1, b1},
              a02 = {b2, b2, b2, b2}, a03 = {b3, b3, b3, b3};
        f32x4 a10 = a00, a11 = a01, a12 = a02, a13 = a03;
#pragma unroll
        for (int ks = 0; ks < 4; ++ks) {
            const int kof = ks * 32 + lg * 8;
            const bf16x8 af0 = *(const bf16x8*)&As[w * 32 + l15][kof];
            const bf16x8 af1 = *(const bf16x8*)&As[w * 32 + 16 + l15][kof];
            const bf16x8 bf0 = *(const bf16x8*)&Bt[l15][kof];
            const bf16x8 bf1 = *(const bf16x8*)&Bt[16 + l15][kof];
            const bf16x8 bf2 = *(const bf16x8*)&Bt[32 + l15][kof];
            const bf16x8 bf3 = *(const bf16x8*)&Bt[48 + l15][kof];
            a00 = __builtin_amdgcn_mfma_f32_16x16x32_bf16(af0, bf0, a00, 0, 0, 0);
            a01 = __builtin_amdgcn_mfma_f32_16x16x32_bf16(af0, bf1, a01, 0, 0, 0);
            a02 = __builtin_amdgcn_mfma_f32_16x16x32_bf16(af0, bf2, a02, 0, 0, 0);
            a03 = __builtin_amdgcn_mfma_f32_16x16x32_bf16(af0, bf3, a03, 0, 0, 0);
            a10 = __builtin_amdgcn_mfma_f32_16x16x32_bf16(af1, bf0, a10, 0, 0, 0);
            a11 = __builtin_amdgcn_mfma_f32_16x16x32_bf16(af1, bf1, a11, 0, 0, 0);
            a12 = __builtin_amdgcn_mfma_f32_16x16x32_bf16(af1, bf2, a12, 0, 0, 0);
            a13 = __builtin_amdgcn_mfma_f32_16x16x32_bf16(af1, bf3, a13, 0, 0, 0);
        }
        __syncthreads();                 // readers done before next Bt restage

        const int r0 = m0 + w * 32 + lg * 4;
        if (sel == 1 || sel == 2) {      // K,V -> bf16 store
            unsigned short* Ob = sel == 1 ? Kb : Vb;
#define STB(ACC, RT, CT)                                                       \
            _Pragma("unroll")                                                  \
            for (int i = 0; i < 4; ++i) {                                      \
                const int gr = r0 + (RT) * 16 + i;                             \
                if (gr < NNODES)                                               \
                    Ob[(size_t)gr * 128 + c0 + (CT) * 16 + l15] = f2bf(ACC[i]);\
            }
            STB(a00, 0, 0) STB(a01, 0, 1) STB(a02, 0, 2) STB(a03, 0, 3)
            STB(a10, 1, 0) STB(a11, 1, 1) STB(a12, 1, 2) STB(a13, 1, 3)
#undef STB
        } else {
            float* O = sel == 0 ? Q : H;
#define ST(ACC, RT, CT)                                                        \
            _Pragma("unroll")                                                  \
            for (int i = 0; i < 4; ++i) {                                      \
                const int gr = r0 + (RT) * 16 + i;                             \
                if (gr < NNODES)                                               \
                    O[(size_t)gr * 128 + c0 + (CT) * 16 + l15] = ACC[i];       \
            }
            ST(a00, 0, 0) ST(a01, 0, 1) ST(a02, 0, 2) ST(a03, 0, 3)
            ST(a10, 1, 0) ST(a11, 1, 1) ST(a12, 1, 2) ST(a13, 1, 3)
#undef ST
        }
    }
}

// --------------------------------------------- per-dst-node online softmax agg
// One WAVE per node; lanes 0-31 process even edge of a pair, lanes 32-63 the
// odd edge. Lane owns a channel QUAD (c=4*(l&31)); head = (l&31)>>3. K,V both
// gathered bf16 (256 B/row each). Dot-reduce: 3 shfl within the 8-lane head
// group + 1 cross-half shfl for the shared max trajectory. Each half keeps
// its own (s, acc) partials; combined once at the end (m identical).
// H holds skip on entry. FUSE_HEAD=false: H <- relu(skip+msg).
// FUSE_HEAD=true: r[n] = dot(relu(skip+msg), wf).
template <bool FUSE_HEAD>
__global__ __launch_bounds__(128)
void attn_agg(const float* __restrict__ Q, const unsigned short* __restrict__ Kb,
              const unsigned short* __restrict__ Vb, float* __restrict__ H,
              const int* __restrict__ rowptr, const int* __restrict__ colsrc,
              const float* __restrict__ wf, float* __restrict__ r) {
    const int n    = blockIdx.x * 2 + (threadIdx.x >> 6);
    const int l    = threadIdx.x & 63;
    const int half = l >> 5;                 // edge slot within pair
    const int c    = (l & 31) * 4;           // channel quad base
    const float4 q4 = *(const float4*)&Q[(size_t)n * 128 + c];
    const float sc_ = 0.17677669529663687f;  // 1/sqrt(32)
    const float q0 = q4.x * sc_, q1 = q4.y * sc_, q2 = q4.z * sc_, q3 = q4.w * sc_;
    const int beg = rowptr[n], end = rowptr[n + 1];
    const int cnt = end - beg;

    float m = -INFINITY, s = 0.f;
    float a0 = 0.f, a1 = 0.f, a2 = 0.f, a3 = 0.f;

    uint2 ku, vu;                            // prefetch slot (this half's edge)
    if (cnt > 0) {
        const int src = colsrc[min(beg + half, end - 1)];
        ku = *(const uint2*)&Kb[(size_t)src * 128 + c];
        vu = *(const uint2*)&Vb[(size_t)src * 128 + c];
    }
    for (int i = beg; i < end; i += 2) {
        const uint2 kc = ku, vc = vu;
        const bool valid = (i + half) < end;
        if (i + 2 < end) {                   // prefetch next pair
            const int srcN = colsrc[min(i + 2 + half, end - 1)];
            ku = *(const uint2*)&Kb[(size_t)srcN * 128 + c];
            vu = *(const uint2*)&Vb[(size_t)srcN * 128 + c];
        }
        const float2 k01 = bf2f2(kc.x), k23 = bf2f2(kc.y);
        float p = fmaf(q0, k01.x, fmaf(q1, k01.y, fmaf(q2, k23.x, q3 * k23.y)));
        p += __shfl_xor(p, 4);
        p += __shfl_xor(p, 2);
        p += __shfl_xor(p, 1);               // head score (8-lane group)
        if (!valid) p = -INFINITY;
        const float pO = __shfl_xor(p, 32);  // other half's score
        const float nm = fmaxf(fmaxf(p, pO), m);
        const float sc = __expf(m - nm);
        const float w  = __expf(p - nm);     // 0 for invalid edge
        s = fmaf(s, sc, w);
        const float2 v01 = bf2f2(vc.x), v23 = bf2f2(vc.y);
        a0 = fmaf(a0, sc, w * v01.x);
        a1 = fmaf(a1, sc, w * v01.y);
        a2 = fmaf(a2, sc, w * v23.x);
        a3 = fmaf(a3, sc, w * v23.y);
        m = nm;
    }
    // combine the two halves (same m trajectory)
    s  += __shfl_xor(s, 32);
    a0 += __shfl_xor(a0, 32);
    a1 += __shfl_xor(a1, 32);
    a2 += __shfl_xor(a2, 32);
    a3 += __shfl_xor(a3, 32);

    const float4 hv = *(const float4*)&H[(size_t)n * 128 + c];
    float o0 = hv.x, o1 = hv.y, o2 = hv.z, o3 = hv.w;
    if (cnt > 0) {
        const float inv = 1.f / s;
        o0 = fmaf(a0, inv, o0);
        o1 = fmaf(a1, inv, o1);
        o2 = fmaf(a2, inv, o2);
        o3 = fmaf(a3, inv, o3);
    }
    o0 = fmaxf(o0, 0.f); o1 = fmaxf(o1, 0.f);
    o2 = fmaxf(o2, 0.f); o3 = fmaxf(o3, 0.f);
    if (!FUSE_HEAD) {
        if (half == 0) {
            float4 o; o.x = o0; o.y = o1; o.z = o2; o.w = o3;
            *(float4*)&H[(size_t)n * 128 + c] = o;
        }
    } else {
        float val = fmaf(o0, wf[c], fmaf(o1, wf[c + 1],
                    fmaf(o2, wf[c + 2], o3 * wf[c + 3])));
        val += __shfl_xor(val, 16);
        val += __shfl_xor(val, 8);
        val += __shfl_xor(val, 4);
        val += __shfl_xor(val, 2);
        val += __shfl_xor(val, 1);           // sum over the 32-lane half
        if (l == 0) r[n] = val;
    }
}

// ----------------------------------------------- per-graph mean (batch sorted)
__global__ __launch_bounds__(256)
void graph_pool(const float* __restrict__ r, const int* __restrict__ batch,
                const float* __restrict__ bf, float* __restrict__ out) {
    const int g = blockIdx.x;
    const int t = threadIdx.x;
    int lo = 0, hi = NNODES;
    while (lo < hi) { int mid = (lo + hi) >> 1; if (batch[mid] < g) lo = mid + 1; else hi = mid; }
    const int beg = lo;
    lo = beg; hi = NNODES;
    while (lo < hi) { int mid = (lo + hi) >> 1; if (batch[mid] < g + 1) lo = mid + 1; else hi = mid; }
    const int end = lo;

    float s = 0.f;
    for (int i = beg + t; i < end; i += 256) s += r[i];
#pragma unroll
    for (int off = 32; off > 0; off >>= 1) s += __shfl_xor(s, off, 64);
    __shared__ float pw[4];
    if ((t & 63) == 0) pw[t >> 6] = s;
    __syncthreads();
    if (t == 0) {
        const float cnt = (float)(end - beg);
        const float tot = pw[0] + pw[1] + pw[2] + pw[3] + cnt * bf[0];
        out[g] = tot / fmaxf(cnt, 1.f);
    }
}

// ---------------------------------------------------------------------- launch
extern "C" void kernel_launch(void* const* d_in, const int* in_sizes, int n_in,
                              void* d_out, int out_size, void* d_ws, size_t ws_size,
                              hipStream_t stream) {
    const float* x     = (const float*)d_in[0];
    const int*   ei    = (const int*)d_in[1];
    const int*   batch = (const int*)d_in[2];
    const float* wq1 = (const float*)d_in[3];  const float* bq1 = (const float*)d_in[4];
    const float* wk1 = (const float*)d_in[5];  const float* bk1 = (const float*)d_in[6];
    const float* wv1 = (const float*)d_in[7];  const float* bv1 = (const float*)d_in[8];
    const float* ws1 = (const float*)d_in[9];  const float* bs1 = (const float*)d_in[10];
    const float* wq2 = (const float*)d_in[11]; const float* bq2 = (const float*)d_in[12];
    const float* wk2 = (const float*)d_in[13]; const float* bk2 = (const float*)d_in[14];
    const float* wv2 = (const float*)d_in[15]; const float* bv2 = (const float*)d_in[16];
    const float* ws2 = (const float*)d_in[17]; const float* bs2 = (const float*)d_in[18];
    const float* wl  = (const float*)d_in[19]; const float* bl  = (const float*)d_in[20];
    const float* wl2 = (const float*)d_in[21]; const float* bl2 = (const float*)d_in[22];

    char* wsb = (char*)d_ws;
    size_t off = 0;
    auto carve = [&](size_t bytes) -> void* {
        void* p = wsb + off;
        off = (off + bytes + 255) & ~(size_t)255;
        return p;
    };
    const size_t NM = (size_t)NNODES * 128 * sizeof(float);   // 25.6 MB
    float* Q      = (float*)carve(NM);
    unsigned short* Kb = (unsigned short*)carve((size_t)NNODES * 128 * 2);
    unsigned short* Vb = (unsigned short*)carve((size_t)NNODES * 128 * 2);
    float* H1     = (float*)carve(NM);
    float* H2     = (float*)carve(NM);
    int*   rowptr = (int*)carve((NNODES + 1) * sizeof(int));
    int*   wpos   = (int*)carve(NNODES * sizeof(int));
    int*   cnt    = (int*)carve(NNODES * sizeof(int));
    int*   colsrc = (int*)carve(NEDGES * sizeof(int));
    int*   bsum   = (int*)carve(256 * sizeof(int));
    int*   boff   = (int*)carve(256 * sizeof(int));
    float* wf     = (float*)carve(129 * sizeof(float));
    float* bf     = wf + 128;
    float* nodeval = (float*)carve(NNODES * sizeof(float));
    unsigned short* Wt1 = (unsigned short*)carve(65536 * sizeof(unsigned short));
    unsigned short* Wt2 = (unsigned short*)carve(65536 * sizeof(unsigned short));

    hipMemsetAsync(cnt, 0, NNODES * sizeof(int), stream);

    count_edges<<<(NEDGES + 255) / 256, 256, 0, stream>>>(ei, cnt);
    scan_pass1<<<SCAN_B, 256, 0, stream>>>(cnt, bsum);
    scan_pass2<<<1, 256, 0, stream>>>(bsum, boff);
    scan_pass3<<<SCAN_B, 256, 0, stream>>>(cnt, boff, rowptr, wpos);
    fill_csr<<<(NEDGES + 255) / 256, 256, 0, stream>>>(ei, wpos, colsrc);
    fuse_wl<<<1, 128, 0, stream>>>(wl, bl, wl2, bl2, wf, bf);
    prep_w<<<dim3(64, 4), 256, 0, stream>>>(wq1, wk1, wv1, ws1, Wt1);
    prep_w<<<dim3(64, 4), 256, 0, stream>>>(wq2, wk2, wv2, ws2, Wt2);

    const int ggrid = (NNODES + 127) / 128;    // 391 blocks
    const int agrid = NNODES / 2;              // 2 nodes (waves) per block
    // layer 1
    gemm_qkvs<<<ggrid, 256, 0, stream>>>(x, Wt1, bq1, bk1, bv1, bs1, Q, Kb, Vb, H1);
    attn_agg<false><<<agrid, 128, 0, stream>>>(Q, Kb, Vb, H1, rowptr, colsrc,
                                               nullptr, nullptr);
    // layer 2
    gemm_qkvs<<<ggrid, 256, 0, stream>>>(H1, Wt2, bq2, bk2, bv2, bs2, Q, Kb, Vb, H2);
    attn_agg<true><<<agrid, 128, 0, stream>>>(Q, Kb, Vb, H2, rowptr, colsrc,
                                              wf, nodeval);
    // per-graph mean over sorted batch ranges (no atomics)
    graph_pool<<<NGRAPHS, 256, 0, stream>>>(nodeval, batch, bf, (float*)d_out);
}

// Round 9
// 392.759 us; speedup vs baseline: 34.4974x; 1.0226x over previous
//
#include <hip/hip_runtime.h>
#include <hip/hip_bf16.h>
#include <math.h>

#define NNODES 50000
#define NEDGES 800000
#define NGRAPHS 128
#define SCAN_B ((NNODES + 255) / 256)   // 196 scan blocks

typedef __attribute__((ext_vector_type(8))) short bf16x8;   // 8 bf16 = 4 VGPR
typedef __attribute__((ext_vector_type(4))) float f32x4;    // MFMA acc

__device__ __forceinline__ unsigned short f2bf(float f) {   // fp32->bf16 RNE
    unsigned int u = __float_as_uint(f);
    return (unsigned short)((u + 0x7FFFu + ((u >> 16) & 1u)) >> 16);
}
__device__ __forceinline__ unsigned pack2bf(float a, float b) {
    return (unsigned)f2bf(a) | ((unsigned)f2bf(b) << 16);
}
__device__ __forceinline__ float2 bf2f2(unsigned int u) {   // bf16x2 -> 2x fp32
    float2 f;
    f.x = __uint_as_float(u << 16);
    f.y = __uint_as_float(u & 0xFFFF0000u);
    return f;
}

// ---------------------------------------------------------------- CSR build
__global__ void count_edges(const int* __restrict__ ei, int* __restrict__ cnt) {
    int e = blockIdx.x * 256 + threadIdx.x;
    if (e < NEDGES) atomicAdd(&cnt[ei[NEDGES + e]], 1);
}

// 3-pass device-wide exclusive scan
__global__ __launch_bounds__(256)
void scan_pass1(const int* __restrict__ cnt, int* __restrict__ bsum) {
    const int t = threadIdx.x;
    const int i = blockIdx.x * 256 + t;
    int v = (i < NNODES) ? cnt[i] : 0;
#pragma unroll
    for (int off = 32; off > 0; off >>= 1) v += __shfl_xor(v, off, 64);
    __shared__ int ws[4];
    if ((t & 63) == 0) ws[t >> 6] = v;
    __syncthreads();
    if (t == 0) bsum[blockIdx.x] = ws[0] + ws[1] + ws[2] + ws[3];
}

__global__ __launch_bounds__(256)
void scan_pass2(const int* __restrict__ bsum, int* __restrict__ boff) {
    const int t = threadIdx.x;
    const int v = (t < SCAN_B) ? bsum[t] : 0;
    __shared__ int a[256];
    a[t] = v;
    __syncthreads();
    for (int off = 1; off < 256; off <<= 1) {
        const int u = (t >= off) ? a[t - off] : 0;
        __syncthreads();
        a[t] += u;
        __syncthreads();
    }
    if (t < SCAN_B) boff[t] = a[t] - v;   // exclusive
}

__global__ __launch_bounds__(256)
void scan_pass3(const int* __restrict__ cnt, const int* __restrict__ boff,
                int* __restrict__ rowptr, int* __restrict__ wpos) {
    const int t = threadIdx.x;
    const int i = blockIdx.x * 256 + t;
    const int v = (i < NNODES) ? cnt[i] : 0;
    __shared__ int a[256];
    a[t] = v;
    __syncthreads();
    for (int off = 1; off < 256; off <<= 1) {
        const int u = (t >= off) ? a[t - off] : 0;
        __syncthreads();
        a[t] += u;
        __syncthreads();
    }
    if (i < NNODES) {
        const int e = boff[blockIdx.x] + a[t] - v;
        rowptr[i] = e;
        wpos[i]   = e;
    }
    if (i == 0) rowptr[NNODES] = NEDGES;
}

__global__ void fill_csr(const int* __restrict__ ei, int* __restrict__ wpos,
                         int* __restrict__ colsrc) {
    int e = blockIdx.x * 256 + threadIdx.x;
    if (e < NEDGES) {
        int d = ei[NEDGES + e];
        int slot = atomicAdd(&wpos[d], 1);
        colsrc[slot] = ei[e];            // store src node id
    }
}

// ------------------------------------------------- fused head weight (wl@wl2)
__global__ void fuse_wl(const float* __restrict__ wl, const float* __restrict__ bl,
                        const float* __restrict__ wl2, const float* __restrict__ bl2,
                        float* __restrict__ wf, float* __restrict__ bf) {
    int t = threadIdx.x;                 // 128 threads
    float s = 0.f;
    for (int j = 0; j < 128; ++j) s += wl[t * 128 + j] * wl2[j];
    wf[t] = s;
    if (t == 0) {
        float s2 = 0.f;
        for (int j = 0; j < 128; ++j) s2 += bl[j] * wl2[j];
        bf[0] = s2 + bl2[0];
    }
}

// --------------------- weight prep: transpose + bf16 convert (both layers)
__global__ void prep_w(const float* __restrict__ wq1, const float* __restrict__ wk1,
                       const float* __restrict__ wv1, const float* __restrict__ ws1,
                       const float* __restrict__ wq2, const float* __restrict__ wk2,
                       const float* __restrict__ wv2, const float* __restrict__ ws2,
                       unsigned short* __restrict__ Wt) {
    const int layer = blockIdx.z;
    const int sel   = blockIdx.y;
    const float* W = layer == 0
        ? (sel == 0 ? wq1 : sel == 1 ? wk1 : sel == 2 ? wv1 : ws1)
        : (sel == 0 ? wq2 : sel == 1 ? wk2 : sel == 2 ? wv2 : ws2);
    const int idx = blockIdx.x * 256 + threadIdx.x;   // 0..16383
    const int col = idx & 127;
    const int k   = idx >> 7;
    Wt[layer * 65536 + sel * 16384 + col * 128 + k] = f2bf(W[k * 128 + col]);
}

// ------------------------------------------------------------ MFMA fused GEMM
// O[sel] = F @ W[sel] + b[sel] via mfma_f32_16x16x32_bf16 (fp32 accum).
// ALL outputs bf16. A staged once (from fp32 layer-1 input or bf16 H1).
// Bt double-buffered: issue next slice's B-loads, then MFMA, then ONE sync.
template <bool A_BF16>
__global__ __launch_bounds__(256)
void gemm_qkvs(const void* __restrict__ Fv, const unsigned short* __restrict__ Wt,
               const float* __restrict__ bq, const float* __restrict__ bk,
               const float* __restrict__ bv, const float* __restrict__ bsk,
               unsigned short* __restrict__ Qb, unsigned short* __restrict__ Kb,
               unsigned short* __restrict__ Vb, unsigned short* __restrict__ Hb) {
    __shared__ __align__(16) unsigned short As[128][136];      // 34.8 KB
    __shared__ __align__(16) unsigned short Bt[2][64][136];    // 2 x 17.4 KB
    const int t    = threadIdx.x;
    const int m0   = blockIdx.x * 128;
    const int lane = t & 63;
    const int w    = t >> 6;            // wave 0..3 -> rows [w*32, w*32+32)
    const int l15  = lane & 15;
    const int lg   = lane >> 4;         // 0..3

    {   // stage A: 128 rows x 128 k
        const int row = t >> 1;
        const int kh  = (t & 1) * 64;
        const int gr  = min(m0 + row, NNODES - 1);   // tail clamp; stores guarded
        if constexpr (A_BF16) {
            const unsigned short* src = &((const unsigned short*)Fv)[(size_t)gr * 128 + kh];
#pragma unroll
            for (int p = 0; p < 8; ++p)
                *(uint4*)&As[row][kh + p * 8] = *(const uint4*)&src[p * 8];
        } else {
            const float* src = &((const float*)Fv)[(size_t)gr * 128 + kh];
#pragma unroll
            for (int p = 0; p < 16; ++p) {
                const float4 v = *(const float4*)&src[p * 4];
                ushort4 u;
                u.x = f2bf(v.x); u.y = f2bf(v.y); u.z = f2bf(v.z); u.w = f2bf(v.w);
                *(ushort4*)&As[row][kh + p * 4] = u;
            }
        }
    }

#define STAGE_B(BUF, SL)                                                       \
    {                                                                          \
        const int sel_ = (SL) >> 1, c0_ = ((SL) & 1) * 64;                     \
        const int col = t >> 2, kb = (t & 3) * 32;                             \
        const unsigned short* src = &Wt[sel_ * 16384 + (c0_ + col) * 128 + kb];\
        _Pragma("unroll")                                                      \
        for (int p = 0; p < 4; ++p)                                            \
            *(uint4*)&Bt[BUF][col][kb + p * 8] = *(const uint4*)&src[p * 8];   \
    }

    STAGE_B(0, 0)
    __syncthreads();                     // As + Bt[0] ready

    for (int sl = 0; sl < 8; ++sl) {
        const int cur = sl & 1;
        if (sl < 7) STAGE_B(cur ^ 1, sl + 1)   // loads in flight during MFMA

        const int sel = sl >> 1;
        const int c0  = (sl & 1) * 64;
        const float* bias = sel == 0 ? bq : sel == 1 ? bk : sel == 2 ? bv : bsk;
        unsigned short* Ob = sel == 0 ? Qb : sel == 1 ? Kb : sel == 2 ? Vb : Hb;

        const float b0 = bias[c0 + l15];
        const float b1 = bias[c0 + 16 + l15];
        const float b2 = bias[c0 + 32 + l15];
        const float b3 = bias[c0 + 48 + l15];
        f32x4 a00 = {b0, b0, b0, b0}, a01 = {b1, b1, b1, b1},
              a02 = {b2, b2, b2, b2}, a03 = {b3, b3, b3, b3};
        f32x4 a10 = a00, a11 = a01, a12 = a02, a13 = a03;
#pragma unroll
        for (int ks = 0; ks < 4; ++ks) {
            const int kof = ks * 32 + lg * 8;
            const bf16x8 af0 = *(const bf16x8*)&As[w * 32 + l15][kof];
            const bf16x8 af1 = *(const bf16x8*)&As[w * 32 + 16 + l15][kof];
            const bf16x8 bf0 = *(const bf16x8*)&Bt[cur][l15][kof];
            const bf16x8 bf1 = *(const bf16x8*)&Bt[cur][16 + l15][kof];
            const bf16x8 bf2 = *(const bf16x8*)&Bt[cur][32 + l15][kof];
            const bf16x8 bf3 = *(const bf16x8*)&Bt[cur][48 + l15][kof];
            a00 = __builtin_amdgcn_mfma_f32_16x16x32_bf16(af0, bf0, a00, 0, 0, 0);
            a01 = __builtin_amdgcn_mfma_f32_16x16x32_bf16(af0, bf1, a01, 0, 0, 0);
            a02 = __builtin_amdgcn_mfma_f32_16x16x32_bf16(af0, bf2, a02, 0, 0, 0);
            a03 = __builtin_amdgcn_mfma_f32_16x16x32_bf16(af0, bf3, a03, 0, 0, 0);
            a10 = __builtin_amdgcn_mfma_f32_16x16x32_bf16(af1, bf0, a10, 0, 0, 0);
            a11 = __builtin_amdgcn_mfma_f32_16x16x32_bf16(af1, bf1, a11, 0, 0, 0);
            a12 = __builtin_amdgcn_mfma_f32_16x16x32_bf16(af1, bf2, a12, 0, 0, 0);
            a13 = __builtin_amdgcn_mfma_f32_16x16x32_bf16(af1, bf3, a13, 0, 0, 0);
        }

        const int r0 = m0 + w * 32 + lg * 4;
#define STB(ACC, RT, CT)                                                       \
        _Pragma("unroll")                                                      \
        for (int i = 0; i < 4; ++i) {                                          \
            const int gr = r0 + (RT) * 16 + i;                                 \
            if (gr < NNODES)                                                   \
                Ob[(size_t)gr * 128 + c0 + (CT) * 16 + l15] = f2bf(ACC[i]);    \
        }
        STB(a00, 0, 0) STB(a01, 0, 1) STB(a02, 0, 2) STB(a03, 0, 3)
        STB(a10, 1, 0) STB(a11, 1, 1) STB(a12, 1, 2) STB(a13, 1, 3)
#undef STB
        __syncthreads();                 // one barrier per slice
    }
#undef STAGE_B
}

// --------------------------------------------- per-dst-node online softmax agg
// One WAVE per node; lanes 0-31 = even edge, lanes 32-63 = odd edge of a pair.
// Lane owns a channel QUAD. Q, K, V, skip-H all bf16; H written bf16.
template <bool FUSE_HEAD>
__global__ __launch_bounds__(128)
void attn_agg(const unsigned short* __restrict__ Qb,
              const unsigned short* __restrict__ Kb,
              const unsigned short* __restrict__ Vb,
              unsigned short* __restrict__ Hb,
              const int* __restrict__ rowptr, const int* __restrict__ colsrc,
              const float* __restrict__ wf, float* __restrict__ r) {
    const int n    = blockIdx.x * 2 + (threadIdx.x >> 6);
    const int l    = threadIdx.x & 63;
    const int half = l >> 5;                 // edge slot within pair
    const int c    = (l & 31) * 4;           // channel quad base
    const uint2 qu = *(const uint2*)&Qb[(size_t)n * 128 + c];
    const float2 q01 = bf2f2(qu.x), q23 = bf2f2(qu.y);
    const float sc_ = 0.17677669529663687f;  // 1/sqrt(32)
    const float q0 = q01.x * sc_, q1 = q01.y * sc_;
    const float q2 = q23.x * sc_, q3 = q23.y * sc_;
    const int beg = rowptr[n], end = rowptr[n + 1];
    const int cnt = end - beg;

    float m = -INFINITY, s = 0.f;
    float a0 = 0.f, a1 = 0.f, a2 = 0.f, a3 = 0.f;

    uint2 ku, vu;                            // prefetch slot (this half's edge)
    if (cnt > 0) {
        const int src = colsrc[min(beg + half, end - 1)];
        ku = *(const uint2*)&Kb[(size_t)src * 128 + c];
        vu = *(const uint2*)&Vb[(size_t)src * 128 + c];
    }
    for (int i = beg; i < end; i += 2) {
        const uint2 kc = ku, vc = vu;
        const bool valid = (i + half) < end;
        if (i + 2 < end) {                   // prefetch next pair
            const int srcN = colsrc[min(i + 2 + half, end - 1)];
            ku = *(const uint2*)&Kb[(size_t)srcN * 128 + c];
            vu = *(const uint2*)&Vb[(size_t)srcN * 128 + c];
        }
        const float2 k01 = bf2f2(kc.x), k23 = bf2f2(kc.y);
        float p = fmaf(q0, k01.x, fmaf(q1, k01.y, fmaf(q2, k23.x, q3 * k23.y)));
        p += __shfl_xor(p, 4);
        p += __shfl_xor(p, 2);
        p += __shfl_xor(p, 1);               // head score (8-lane group)
        if (!valid) p = -INFINITY;
        const float pO = __shfl_xor(p, 32);  // other half's score
        const float nm = fmaxf(fmaxf(p, pO), m);
        const float sc = __expf(m - nm);
        const float w  = __expf(p - nm);     // 0 for invalid edge
        s = fmaf(s, sc, w);
        const float2 v01 = bf2f2(vc.x), v23 = bf2f2(vc.y);
        a0 = fmaf(a0, sc, w * v01.x);
        a1 = fmaf(a1, sc, w * v01.y);
        a2 = fmaf(a2, sc, w * v23.x);
        a3 = fmaf(a3, sc, w * v23.y);
        m = nm;
    }
    // combine the two halves (same m trajectory)
    s  += __shfl_xor(s, 32);
    a0 += __shfl_xor(a0, 32);
    a1 += __shfl_xor(a1, 32);
    a2 += __shfl_xor(a2, 32);
    a3 += __shfl_xor(a3, 32);

    const uint2 hu = *(const uint2*)&Hb[(size_t)n * 128 + c];
    const float2 h01 = bf2f2(hu.x), h23 = bf2f2(hu.y);
    float o0 = h01.x, o1 = h01.y, o2 = h23.x, o3 = h23.y;
    if (cnt > 0) {
        const float inv = 1.f / s;
        o0 = fmaf(a0, inv, o0);
        o1 = fmaf(a1, inv, o1);
        o2 = fmaf(a2, inv, o2);
        o3 = fmaf(a3, inv, o3);
    }
    o0 = fmaxf(o0, 0.f); o1 = fmaxf(o1, 0.f);
    o2 = fmaxf(o2, 0.f); o3 = fmaxf(o3, 0.f);
    if (!FUSE_HEAD) {
        if (half == 0) {
            uint2 o;
            o.x = pack2bf(o0, o1);
            o.y = pack2bf(o2, o3);
            *(uint2*)&Hb[(size_t)n * 128 + c] = o;
        }
    } else {
        const float4 w4 = *(const float4*)&wf[c];
        float val = fmaf(o0, w4.x, fmaf(o1, w4.y, fmaf(o2, w4.z, o3 * w4.w)));
        val += __shfl_xor(val, 16);
        val += __shfl_xor(val, 8);
        val += __shfl_xor(val, 4);
        val += __shfl_xor(val, 2);
        val += __shfl_xor(val, 1);           // sum over the 32-lane half
        if (l == 0) r[n] = val;
    }
}

// ----------------------------------------------- per-graph mean (batch sorted)
__global__ __launch_bounds__(256)
void graph_pool(const float* __restrict__ r, const int* __restrict__ batch,
                const float* __restrict__ bf, float* __restrict__ out) {
    const int g = blockIdx.x;
    const int t = threadIdx.x;
    int lo = 0, hi = NNODES;
    while (lo < hi) { int mid = (lo + hi) >> 1; if (batch[mid] < g) lo = mid + 1; else hi = mid; }
    const int beg = lo;
    lo = beg; hi = NNODES;
    while (lo < hi) { int mid = (lo + hi) >> 1; if (batch[mid] < g + 1) lo = mid + 1; else hi = mid; }
    const int end = lo;

    float s = 0.f;
    for (int i = beg + t; i < end; i += 256) s += r[i];
#pragma unroll
    for (int off = 32; off > 0; off >>= 1) s += __shfl_xor(s, off, 64);
    __shared__ float pw[4];
    if ((t & 63) == 0) pw[t >> 6] = s;
    __syncthreads();
    if (t == 0) {
        const float cnt = (float)(end - beg);
        const float tot = pw[0] + pw[1] + pw[2] + pw[3] + cnt * bf[0];
        out[g] = tot / fmaxf(cnt, 1.f);
    }
}

// ---------------------------------------------------------------------- launch
extern "C" void kernel_launch(void* const* d_in, const int* in_sizes, int n_in,
                              void* d_out, int out_size, void* d_ws, size_t ws_size,
                              hipStream_t stream) {
    const float* x     = (const float*)d_in[0];
    const int*   ei    = (const int*)d_in[1];
    const int*   batch = (const int*)d_in[2];
    const float* wq1 = (const float*)d_in[3];  const float* bq1 = (const float*)d_in[4];
    const float* wk1 = (const float*)d_in[5];  const float* bk1 = (const float*)d_in[6];
    const float* wv1 = (const float*)d_in[7];  const float* bv1 = (const float*)d_in[8];
    const float* ws1 = (const float*)d_in[9];  const float* bs1 = (const float*)d_in[10];
    const float* wq2 = (const float*)d_in[11]; const float* bq2 = (const float*)d_in[12];
    const float* wk2 = (const float*)d_in[13]; const float* bk2 = (const float*)d_in[14];
    const float* wv2 = (const float*)d_in[15]; const float* bv2 = (const float*)d_in[16];
    const float* ws2 = (const float*)d_in[17]; const float* bs2 = (const float*)d_in[18];
    const float* wl  = (const float*)d_in[19]; const float* bl  = (const float*)d_in[20];
    const float* wl2 = (const float*)d_in[21]; const float* bl2 = (const float*)d_in[22];

    char* wsb = (char*)d_ws;
    size_t off = 0;
    auto carve = [&](size_t bytes) -> void* {
        void* p = wsb + off;
        off = (off + bytes + 255) & ~(size_t)255;
        return p;
    };
    const size_t NB = (size_t)NNODES * 128 * 2;   // bf16 node matrix: 12.8 MB
    unsigned short* Qb = (unsigned short*)carve(NB);
    unsigned short* Kb = (unsigned short*)carve(NB);
    unsigned short* Vb = (unsigned short*)carve(NB);
    unsigned short* H1 = (unsigned short*)carve(NB);
    unsigned short* H2 = (unsigned short*)carve(NB);
    int*   rowptr = (int*)carve((NNODES + 1) * sizeof(int));
    int*   wpos   = (int*)carve(NNODES * sizeof(int));
    int*   cnt    = (int*)carve(NNODES * sizeof(int));
    int*   colsrc = (int*)carve(NEDGES * sizeof(int));
    int*   bsum   = (int*)carve(256 * sizeof(int));
    int*   boff   = (int*)carve(256 * sizeof(int));
    float* wf     = (float*)carve(129 * sizeof(float));
    float* bf     = wf + 128;
    float* nodeval = (float*)carve(NNODES * sizeof(float));
    unsigned short* Wt = (unsigned short*)carve(131072 * sizeof(unsigned short));

    hipMemsetAsync(cnt, 0, NNODES * sizeof(int), stream);

    count_edges<<<(NEDGES + 255) / 256, 256, 0, stream>>>(ei, cnt);
    scan_pass1<<<SCAN_B, 256, 0, stream>>>(cnt, bsum);
    scan_pass2<<<1, 256, 0, stream>>>(bsum, boff);
    scan_pass3<<<SCAN_B, 256, 0, stream>>>(cnt, boff, rowptr, wpos);
    fill_csr<<<(NEDGES + 255) / 256, 256, 0, stream>>>(ei, wpos, colsrc);
    fuse_wl<<<1, 128, 0, stream>>>(wl, bl, wl2, bl2, wf, bf);
    prep_w<<<dim3(64, 4, 2), 256, 0, stream>>>(wq1, wk1, wv1, ws1,
                                               wq2, wk2, wv2, ws2, Wt);

    const int ggrid = (NNODES + 127) / 128;    // 391 blocks
    const int agrid = NNODES / 2;              // 2 nodes (waves) per block
    // layer 1
    gemm_qkvs<false><<<ggrid, 256, 0, stream>>>(x, Wt, bq1, bk1, bv1, bs1,
                                                Qb, Kb, Vb, H1);
    attn_agg<false><<<agrid, 128, 0, stream>>>(Qb, Kb, Vb, H1, rowptr, colsrc,
                                               nullptr, nullptr);
    // layer 2
    gemm_qkvs<true><<<ggrid, 256, 0, stream>>>(H1, Wt + 65536, bq2, bk2, bv2, bs2,
                                               Qb, Kb, Vb, H2);
    attn_agg<true><<<agrid, 128, 0, stream>>>(Qb, Kb, Vb, H2, rowptr, colsrc,
                                              wf, nodeval);
    // per-graph mean over sorted batch ranges (no atomics)
    graph_pool<<<NGRAPHS, 256, 0, stream>>>(nodeval, batch, bf, (float*)d_out);
}

// Round 10
// 369.597 us; speedup vs baseline: 36.6593x; 1.0627x over previous
//
#include <hip/hip_runtime.h>
#include <hip/hip_bf16.h>
#include <math.h>

#define NNODES 50000
#define NEDGES 800000
#define NGRAPHS 128
#define SCAN_B ((NNODES + 255) / 256)   // 196 scan blocks

typedef __attribute__((ext_vector_type(8))) short bf16x8;   // 8 bf16 = 4 VGPR
typedef __attribute__((ext_vector_type(4))) float f32x4;    // MFMA acc

__device__ __forceinline__ unsigned short f2bf(float f) {   // fp32->bf16 RNE
    unsigned int u = __float_as_uint(f);
    return (unsigned short)((u + 0x7FFFu + ((u >> 16) & 1u)) >> 16);
}
__device__ __forceinline__ unsigned pack2bf(float a, float b) {
    return (unsigned)f2bf(a) | ((unsigned)f2bf(b) << 16);
}
__device__ __forceinline__ float2 bf2f2(unsigned int u) {   // bf16x2 -> 2x fp32
    float2 f;
    f.x = __uint_as_float(u << 16);
    f.y = __uint_as_float(u & 0xFFFF0000u);
    return f;
}

// ---------------------------------------------------------------- CSR build
__global__ void count_edges(const int* __restrict__ ei, int* __restrict__ cnt) {
    int e = blockIdx.x * 256 + threadIdx.x;
    if (e < NEDGES) atomicAdd(&cnt[ei[NEDGES + e]], 1);
}

// 3-pass device-wide exclusive scan
__global__ __launch_bounds__(256)
void scan_pass1(const int* __restrict__ cnt, int* __restrict__ bsum) {
    const int t = threadIdx.x;
    const int i = blockIdx.x * 256 + t;
    int v = (i < NNODES) ? cnt[i] : 0;
#pragma unroll
    for (int off = 32; off > 0; off >>= 1) v += __shfl_xor(v, off, 64);
    __shared__ int ws[4];
    if ((t & 63) == 0) ws[t >> 6] = v;
    __syncthreads();
    if (t == 0) bsum[blockIdx.x] = ws[0] + ws[1] + ws[2] + ws[3];
}

__global__ __launch_bounds__(256)
void scan_pass2(const int* __restrict__ bsum, int* __restrict__ boff) {
    const int t = threadIdx.x;
    const int v = (t < SCAN_B) ? bsum[t] : 0;
    __shared__ int a[256];
    a[t] = v;
    __syncthreads();
    for (int off = 1; off < 256; off <<= 1) {
        const int u = (t >= off) ? a[t - off] : 0;
        __syncthreads();
        a[t] += u;
        __syncthreads();
    }
    if (t < SCAN_B) boff[t] = a[t] - v;   // exclusive
}

__global__ __launch_bounds__(256)
void scan_pass3(const int* __restrict__ cnt, const int* __restrict__ boff,
                int* __restrict__ rowptr, int* __restrict__ wpos) {
    const int t = threadIdx.x;
    const int i = blockIdx.x * 256 + t;
    const int v = (i < NNODES) ? cnt[i] : 0;
    __shared__ int a[256];
    a[t] = v;
    __syncthreads();
    for (int off = 1; off < 256; off <<= 1) {
        const int u = (t >= off) ? a[t - off] : 0;
        __syncthreads();
        a[t] += u;
        __syncthreads();
    }
    if (i < NNODES) {
        const int e = boff[blockIdx.x] + a[t] - v;
        rowptr[i] = e;
        wpos[i]   = e;
    }
    if (i == 0) rowptr[NNODES] = NEDGES;
}

__global__ void fill_csr(const int* __restrict__ ei, int* __restrict__ wpos,
                         int* __restrict__ colsrc) {
    int e = blockIdx.x * 256 + threadIdx.x;
    if (e < NEDGES) {
        int d = ei[NEDGES + e];
        int slot = atomicAdd(&wpos[d], 1);
        colsrc[slot] = ei[e];            // store src node id
    }
}

// ------------------- fused head weight (wl@wl2), parallel: 129 blocks x 64
__global__ __launch_bounds__(64)
void fuse_wl(const float* __restrict__ wl, const float* __restrict__ bl,
             const float* __restrict__ wl2, const float* __restrict__ bl2,
             float* __restrict__ wf, float* __restrict__ bf) {
    const int g = blockIdx.x;
    const int l = threadIdx.x;
    const float* row = (g < 128) ? &wl[g * 128] : bl;
    float s = row[l] * wl2[l] + row[64 + l] * wl2[64 + l];
#pragma unroll
    for (int off = 32; off > 0; off >>= 1) s += __shfl_xor(s, off, 64);
    if (l == 0) {
        if (g < 128) wf[g] = s;
        else         bf[0] = s + bl2[0];
    }
}

// --------------------- weight prep: transpose + bf16 convert (both layers)
__global__ void prep_w(const float* __restrict__ wq1, const float* __restrict__ wk1,
                       const float* __restrict__ wv1, const float* __restrict__ ws1,
                       const float* __restrict__ wq2, const float* __restrict__ wk2,
                       const float* __restrict__ wv2, const float* __restrict__ ws2,
                       unsigned short* __restrict__ Wt) {
    const int layer = blockIdx.z;
    const int sel   = blockIdx.y;
    const float* W = layer == 0
        ? (sel == 0 ? wq1 : sel == 1 ? wk1 : sel == 2 ? wv1 : ws1)
        : (sel == 0 ? wq2 : sel == 1 ? wk2 : sel == 2 ? wv2 : ws2);
    const int idx = blockIdx.x * 256 + threadIdx.x;   // 0..16383
    const int col = idx & 127;
    const int k   = idx >> 7;
    Wt[layer * 65536 + sel * 16384 + col * 128 + k] = f2bf(W[k * 128 + col]);
}

// ------------------------------------------------------------ MFMA fused GEMM
// O[sel] = F @ W[sel] + b[sel] via mfma_f32_16x16x32_bf16 (fp32 accum).
// ALL outputs bf16. A staged once (from fp32 layer-1 input or bf16 H1).
// Bt double-buffered: issue next slice's B-loads, then MFMA, then ONE sync.
template <bool A_BF16>
__global__ __launch_bounds__(256)
void gemm_qkvs(const void* __restrict__ Fv, const unsigned short* __restrict__ Wt,
               const float* __restrict__ bq, const float* __restrict__ bk,
               const float* __restrict__ bv, const float* __restrict__ bsk,
               unsigned short* __restrict__ Qb, unsigned short* __restrict__ Kb,
               unsigned short* __restrict__ Vb, unsigned short* __restrict__ Hb) {
    __shared__ __align__(16) unsigned short As[128][136];      // 34.8 KB
    __shared__ __align__(16) unsigned short Bt[2][64][136];    // 2 x 17.4 KB
    const int t    = threadIdx.x;
    const int m0   = blockIdx.x * 128;
    const int lane = t & 63;
    const int w    = t >> 6;            // wave 0..3 -> rows [w*32, w*32+32)
    const int l15  = lane & 15;
    const int lg   = lane >> 4;         // 0..3

    {   // stage A: 128 rows x 128 k
        const int row = t >> 1;
        const int kh  = (t & 1) * 64;
        const int gr  = min(m0 + row, NNODES - 1);   // tail clamp; stores guarded
        if constexpr (A_BF16) {
            const unsigned short* src = &((const unsigned short*)Fv)[(size_t)gr * 128 + kh];
#pragma unroll
            for (int p = 0; p < 8; ++p)
                *(uint4*)&As[row][kh + p * 8] = *(const uint4*)&src[p * 8];
        } else {
            const float* src = &((const float*)Fv)[(size_t)gr * 128 + kh];
#pragma unroll
            for (int p = 0; p < 16; ++p) {
                const float4 v = *(const float4*)&src[p * 4];
                ushort4 u;
                u.x = f2bf(v.x); u.y = f2bf(v.y); u.z = f2bf(v.z); u.w = f2bf(v.w);
                *(ushort4*)&As[row][kh + p * 4] = u;
            }
        }
    }

#define STAGE_B(BUF, SL)                                                       \
    {                                                                          \
        const int sel_ = (SL) >> 1, c0_ = ((SL) & 1) * 64;                     \
        const int col = t >> 2, kb = (t & 3) * 32;                             \
        const unsigned short* src = &Wt[sel_ * 16384 + (c0_ + col) * 128 + kb];\
        _Pragma("unroll")                                                      \
        for (int p = 0; p < 4; ++p)                                            \
            *(uint4*)&Bt[BUF][col][kb + p * 8] = *(const uint4*)&src[p * 8];   \
    }

    STAGE_B(0, 0)
    __syncthreads();                     // As + Bt[0] ready

    for (int sl = 0; sl < 8; ++sl) {
        const int cur = sl & 1;
        if (sl < 7) STAGE_B(cur ^ 1, sl + 1)   // loads in flight during MFMA

        const int sel = sl >> 1;
        const int c0  = (sl & 1) * 64;
        const float* bias = sel == 0 ? bq : sel == 1 ? bk : sel == 2 ? bv : bsk;
        unsigned short* Ob = sel == 0 ? Qb : sel == 1 ? Kb : sel == 2 ? Vb : Hb;

        const float b0 = bias[c0 + l15];
        const float b1 = bias[c0 + 16 + l15];
        const float b2 = bias[c0 + 32 + l15];
        const float b3 = bias[c0 + 48 + l15];
        f32x4 a00 = {b0, b0, b0, b0}, a01 = {b1, b1, b1, b1},
              a02 = {b2, b2, b2, b2}, a03 = {b3, b3, b3, b3};
        f32x4 a10 = a00, a11 = a01, a12 = a02, a13 = a03;
#pragma unroll
        for (int ks = 0; ks < 4; ++ks) {
            const int kof = ks * 32 + lg * 8;
            const bf16x8 af0 = *(const bf16x8*)&As[w * 32 + l15][kof];
            const bf16x8 af1 = *(const bf16x8*)&As[w * 32 + 16 + l15][kof];
            const bf16x8 bf0 = *(const bf16x8*)&Bt[cur][l15][kof];
            const bf16x8 bf1 = *(const bf16x8*)&Bt[cur][16 + l15][kof];
            const bf16x8 bf2 = *(const bf16x8*)&Bt[cur][32 + l15][kof];
            const bf16x8 bf3 = *(const bf16x8*)&Bt[cur][48 + l15][kof];
            a00 = __builtin_amdgcn_mfma_f32_16x16x32_bf16(af0, bf0, a00, 0, 0, 0);
            a01 = __builtin_amdgcn_mfma_f32_16x16x32_bf16(af0, bf1, a01, 0, 0, 0);
            a02 = __builtin_amdgcn_mfma_f32_16x16x32_bf16(af0, bf2, a02, 0, 0, 0);
            a03 = __builtin_amdgcn_mfma_f32_16x16x32_bf16(af0, bf3, a03, 0, 0, 0);
            a10 = __builtin_amdgcn_mfma_f32_16x16x32_bf16(af1, bf0, a10, 0, 0, 0);
            a11 = __builtin_amdgcn_mfma_f32_16x16x32_bf16(af1, bf1, a11, 0, 0, 0);
            a12 = __builtin_amdgcn_mfma_f32_16x16x32_bf16(af1, bf2, a12, 0, 0, 0);
            a13 = __builtin_amdgcn_mfma_f32_16x16x32_bf16(af1, bf3, a13, 0, 0, 0);
        }

        const int r0 = m0 + w * 32 + lg * 4;
#define STB(ACC, RT, CT)                                                       \
        _Pragma("unroll")                                                      \
        for (int i = 0; i < 4; ++i) {                                          \
            const int gr = r0 + (RT) * 16 + i;                                 \
            if (gr < NNODES)                                                   \
                Ob[(size_t)gr * 128 + c0 + (CT) * 16 + l15] = f2bf(ACC[i]);    \
        }
        STB(a00, 0, 0) STB(a01, 0, 1) STB(a02, 0, 2) STB(a03, 0, 3)
        STB(a10, 1, 0) STB(a11, 1, 1) STB(a12, 1, 2) STB(a13, 1, 3)
#undef STB
        __syncthreads();                 // one barrier per slice
    }
#undef STAGE_B
}

// --------------------------------------------- per-dst-node online softmax agg
// One WAVE per node; 4 edge slots x 16 lanes; lane owns a channel OCTET
// (c = (l&15)*8, head = (l&15)>>2). Defer-max (T13): m rescale only when
// !__all(p <= m+8), exp2-domain scores (log2e/sqrt(32) folded into Q).
// All node tensors bf16. FUSE_HEAD=false: H <- relu(skip+msg) (bf16).
// FUSE_HEAD=true: r[n] = dot(relu(skip+msg), wf).
template <bool FUSE_HEAD>
__global__ __launch_bounds__(128)
void attn_agg(const unsigned short* __restrict__ Qb,
              const unsigned short* __restrict__ Kb,
              const unsigned short* __restrict__ Vb,
              unsigned short* __restrict__ Hb,
              const int* __restrict__ rowptr, const int* __restrict__ colsrc,
              const float* __restrict__ wf, float* __restrict__ r) {
    const int n = blockIdx.x * 2 + (threadIdx.x >> 6);
    const int l = threadIdx.x & 63;
    const int e = l >> 4;                    // edge slot 0..3
    const int c = (l & 15) * 8;              // channel octet base
    const uint4 qu = *(const uint4*)&Qb[(size_t)n * 128 + c];
    const float S = 0.17677669529663687f * 1.4426950408889634f; // log2e/sqrt(32)
    const float2 t01 = bf2f2(qu.x), t23 = bf2f2(qu.y);
    const float2 t45 = bf2f2(qu.z), t67 = bf2f2(qu.w);
    const float q0 = t01.x * S, q1 = t01.y * S, q2 = t23.x * S, q3 = t23.y * S;
    const float q4 = t45.x * S, q5 = t45.y * S, q6 = t67.x * S, q7 = t67.y * S;
    const int beg = rowptr[n], end = rowptr[n + 1];
    const int cnt = end - beg;

    float m = -INFINITY, s = 0.f;
    float a0 = 0.f, a1 = 0.f, a2 = 0.f, a3 = 0.f;
    float a4 = 0.f, a5 = 0.f, a6 = 0.f, a7 = 0.f;

    uint4 ku, vu;                            // prefetch (this slot's edge)
    if (cnt > 0) {
        const int src = colsrc[min(beg + e, end - 1)];
        ku = *(const uint4*)&Kb[(size_t)src * 128 + c];
        vu = *(const uint4*)&Vb[(size_t)src * 128 + c];
    }
    for (int i = beg; i < end; i += 4) {
        const uint4 kc = ku, vc = vu;
        const bool valid = (i + e) < end;
        if (i + 4 < end) {                   // prefetch next 4 edges
            const int srcN = colsrc[min(i + 4 + e, end - 1)];
            ku = *(const uint4*)&Kb[(size_t)srcN * 128 + c];
            vu = *(const uint4*)&Vb[(size_t)srcN * 128 + c];
        }
        const float2 k01 = bf2f2(kc.x), k23 = bf2f2(kc.y);
        const float2 k45 = bf2f2(kc.z), k67 = bf2f2(kc.w);
        float p = q0 * k01.x;
        p = fmaf(q1, k01.y, p); p = fmaf(q2, k23.x, p); p = fmaf(q3, k23.y, p);
        p = fmaf(q4, k45.x, p); p = fmaf(q5, k45.y, p); p = fmaf(q6, k67.x, p);
        p = fmaf(q7, k67.y, p);
        p += __shfl_xor(p, 2);
        p += __shfl_xor(p, 1);               // per-head edge score (4-lane group)
        if (!valid) p = -INFINITY;
        if (!__all(p <= m + 8.f)) {          // rare rescale (always on iter 0)
            float pm = fmaxf(p, __shfl_xor(p, 16));
            pm = fmaxf(pm, __shfl_xor(pm, 32));      // max over 4 edge slots
            const float nm = fmaxf(m, pm);
            const float sc = exp2f(m - nm);          // 0 on first iteration
            s *= sc;
            a0 *= sc; a1 *= sc; a2 *= sc; a3 *= sc;
            a4 *= sc; a5 *= sc; a6 *= sc; a7 *= sc;
            m = nm;
        }
        const float w = exp2f(p - m);        // 0 for invalid edge
        s += w;
        const float2 v01 = bf2f2(vc.x), v23 = bf2f2(vc.y);
        const float2 v45 = bf2f2(vc.z), v67 = bf2f2(vc.w);
        a0 = fmaf(w, v01.x, a0); a1 = fmaf(w, v01.y, a1);
        a2 = fmaf(w, v23.x, a2); a3 = fmaf(w, v23.y, a3);
        a4 = fmaf(w, v45.x, a4); a5 = fmaf(w, v45.y, a5);
        a6 = fmaf(w, v67.x, a6); a7 = fmaf(w, v67.y, a7);
    }
    // combine the 4 edge slots (identical m)
    s  += __shfl_xor(s, 16);  s  += __shfl_xor(s, 32);
    a0 += __shfl_xor(a0, 16); a0 += __shfl_xor(a0, 32);
    a1 += __shfl_xor(a1, 16); a1 += __shfl_xor(a1, 32);
    a2 += __shfl_xor(a2, 16); a2 += __shfl_xor(a2, 32);
    a3 += __shfl_xor(a3, 16); a3 += __shfl_xor(a3, 32);
    a4 += __shfl_xor(a4, 16); a4 += __shfl_xor(a4, 32);
    a5 += __shfl_xor(a5, 16); a5 += __shfl_xor(a5, 32);
    a6 += __shfl_xor(a6, 16); a6 += __shfl_xor(a6, 32);
    a7 += __shfl_xor(a7, 16); a7 += __shfl_xor(a7, 32);

    const uint4 hu = *(const uint4*)&Hb[(size_t)n * 128 + c];
    const float2 h01 = bf2f2(hu.x), h23 = bf2f2(hu.y);
    const float2 h45 = bf2f2(hu.z), h67 = bf2f2(hu.w);
    float o0 = h01.x, o1 = h01.y, o2 = h23.x, o3 = h23.y;
    float o4 = h45.x, o5 = h45.y, o6 = h67.x, o7 = h67.y;
    if (cnt > 0) {
        const float inv = 1.f / s;
        o0 = fmaf(a0, inv, o0); o1 = fmaf(a1, inv, o1);
        o2 = fmaf(a2, inv, o2); o3 = fmaf(a3, inv, o3);
        o4 = fmaf(a4, inv, o4); o5 = fmaf(a5, inv, o5);
        o6 = fmaf(a6, inv, o6); o7 = fmaf(a7, inv, o7);
    }
    o0 = fmaxf(o0, 0.f); o1 = fmaxf(o1, 0.f); o2 = fmaxf(o2, 0.f);
    o3 = fmaxf(o3, 0.f); o4 = fmaxf(o4, 0.f); o5 = fmaxf(o5, 0.f);
    o6 = fmaxf(o6, 0.f); o7 = fmaxf(o7, 0.f);
    if (!FUSE_HEAD) {
        if (e == 0) {                        // one slot writes the octet
            uint4 o;
            o.x = pack2bf(o0, o1); o.y = pack2bf(o2, o3);
            o.z = pack2bf(o4, o5); o.w = pack2bf(o6, o7);
            *(uint4*)&Hb[(size_t)n * 128 + c] = o;
        }
    } else {
        const float4 wA = *(const float4*)&wf[c];
        const float4 wB = *(const float4*)&wf[c + 4];
        float val = fmaf(o0, wA.x, fmaf(o1, wA.y, fmaf(o2, wA.z, o3 * wA.w)));
        val = fmaf(o4, wB.x, fmaf(o5, wB.y, fmaf(o6, wB.z, fmaf(o7, wB.w, val))));
        val += __shfl_xor(val, 8);
        val += __shfl_xor(val, 4);
        val += __shfl_xor(val, 2);
        val += __shfl_xor(val, 1);           // sum over the 16-lane octet group
        if (l == 0) r[n] = val;
    }
}

// ----------------------------------------------- per-graph mean (batch sorted)
__global__ __launch_bounds__(256)
void graph_pool(const float* __restrict__ r, const int* __restrict__ batch,
                const float* __restrict__ bf, float* __restrict__ out) {
    const int g = blockIdx.x;
    const int t = threadIdx.x;
    int lo = 0, hi = NNODES;
    while (lo < hi) { int mid = (lo + hi) >> 1; if (batch[mid] < g) lo = mid + 1; else hi = mid; }
    const int beg = lo;
    lo = beg; hi = NNODES;
    while (lo < hi) { int mid = (lo + hi) >> 1; if (batch[mid] < g + 1) lo = mid + 1; else hi = mid; }
    const int end = lo;

    float s = 0.f;
    for (int i = beg + t; i < end; i += 256) s += r[i];
#pragma unroll
    for (int off = 32; off > 0; off >>= 1) s += __shfl_xor(s, off, 64);
    __shared__ float pw[4];
    if ((t & 63) == 0) pw[t >> 6] = s;
    __syncthreads();
    if (t == 0) {
        const float cnt = (float)(end - beg);
        const float tot = pw[0] + pw[1] + pw[2] + pw[3] + cnt * bf[0];
        out[g] = tot / fmaxf(cnt, 1.f);
    }
}

// ---------------------------------------------------------------------- launch
extern "C" void kernel_launch(void* const* d_in, const int* in_sizes, int n_in,
                              void* d_out, int out_size, void* d_ws, size_t ws_size,
                              hipStream_t stream) {
    const float* x     = (const float*)d_in[0];
    const int*   ei    = (const int*)d_in[1];
    const int*   batch = (const int*)d_in[2];
    const float* wq1 = (const float*)d_in[3];  const float* bq1 = (const float*)d_in[4];
    const float* wk1 = (const float*)d_in[5];  const float* bk1 = (const float*)d_in[6];
    const float* wv1 = (const float*)d_in[7];  const float* bv1 = (const float*)d_in[8];
    const float* ws1 = (const float*)d_in[9];  const float* bs1 = (const float*)d_in[10];
    const float* wq2 = (const float*)d_in[11]; const float* bq2 = (const float*)d_in[12];
    const float* wk2 = (const float*)d_in[13]; const float* bk2 = (const float*)d_in[14];
    const float* wv2 = (const float*)d_in[15]; const float* bv2 = (const float*)d_in[16];
    const float* ws2 = (const float*)d_in[17]; const float* bs2 = (const float*)d_in[18];
    const float* wl  = (const float*)d_in[19]; const float* bl  = (const float*)d_in[20];
    const float* wl2 = (const float*)d_in[21]; const float* bl2 = (const float*)d_in[22];

    char* wsb = (char*)d_ws;
    size_t off = 0;
    auto carve = [&](size_t bytes) -> void* {
        void* p = wsb + off;
        off = (off + bytes + 255) & ~(size_t)255;
        return p;
    };
    const size_t NB = (size_t)NNODES * 128 * 2;   // bf16 node matrix: 12.8 MB
    unsigned short* Qb = (unsigned short*)carve(NB);
    unsigned short* Kb = (unsigned short*)carve(NB);
    unsigned short* Vb = (unsigned short*)carve(NB);
    unsigned short* H1 = (unsigned short*)carve(NB);
    unsigned short* H2 = (unsigned short*)carve(NB);
    int*   rowptr = (int*)carve((NNODES + 1) * sizeof(int));
    int*   wpos   = (int*)carve(NNODES * sizeof(int));
    int*   cnt    = (int*)carve(NNODES * sizeof(int));
    int*   colsrc = (int*)carve(NEDGES * sizeof(int));
    int*   bsum   = (int*)carve(256 * sizeof(int));
    int*   boff   = (int*)carve(256 * sizeof(int));
    float* wf     = (float*)carve(129 * sizeof(float));
    float* bf     = wf + 128;
    float* nodeval = (float*)carve(NNODES * sizeof(float));
    unsigned short* Wt = (unsigned short*)carve(131072 * sizeof(unsigned short));

    hipMemsetAsync(cnt, 0, NNODES * sizeof(int), stream);

    count_edges<<<(NEDGES + 255) / 256, 256, 0, stream>>>(ei, cnt);
    scan_pass1<<<SCAN_B, 256, 0, stream>>>(cnt, bsum);
    scan_pass2<<<1, 256, 0, stream>>>(bsum, boff);
    scan_pass3<<<SCAN_B, 256, 0, stream>>>(cnt, boff, rowptr, wpos);
    fill_csr<<<(NEDGES + 255) / 256, 256, 0, stream>>>(ei, wpos, colsrc);
    fuse_wl<<<129, 64, 0, stream>>>(wl, bl, wl2, bl2, wf, bf);
    prep_w<<<dim3(64, 4, 2), 256, 0, stream>>>(wq1, wk1, wv1, ws1,
                                               wq2, wk2, wv2, ws2, Wt);

    const int ggrid = (NNODES + 127) / 128;    // 391 blocks
    const int agrid = NNODES / 2;              // 2 nodes (waves) per block
    // layer 1
    gemm_qkvs<false><<<ggrid, 256, 0, stream>>>(x, Wt, bq1, bk1, bv1, bs1,
                                                Qb, Kb, Vb, H1);
    attn_agg<false><<<agrid, 128, 0, stream>>>(Qb, Kb, Vb, H1, rowptr, colsrc,
                                               nullptr, nullptr);
    // layer 2
    gemm_qkvs<true><<<ggrid, 256, 0, stream>>>(H1, Wt + 65536, bq2, bk2, bv2, bs2,
                                               Qb, Kb, Vb, H2);
    attn_agg<true><<<agrid, 128, 0, stream>>>(Qb, Kb, Vb, H2, rowptr, colsrc,
                                              wf, nodeval);
    // per-graph mean over sorted batch ranges (no atomics)
    graph_pool<<<NGRAPHS, 256, 0, stream>>>(nodeval, batch, bf, (float*)d_out);
}